// Round 10
// baseline (662.882 us; speedup 1.0000x reference)
//
#include <hip/hip_runtime.h>
#include <cstdint>
#include <cstddef>

// Problem constants
#define NB 256
#define SQ 500
#define NROWS (NB * SQ)   // 128000
#define DQ 128
#define DV 256
#define MM 50
#define FF 512
#define NQA 20096         // padded distinct qa indices (2*NQ+1 = 20001 -> 157*128)
#define WSTRIDE 52        // padded w-row stride (16B aligned)
#define WT 10             // scan LDS tile: steps per stage

typedef _Float16 half8 __attribute__((ext_vector_type(8)));
typedef float floatx4 __attribute__((ext_vector_type(4)));
typedef float f2 __attribute__((ext_vector_type(2)));
typedef unsigned int u32;
typedef unsigned short u16;

typedef __attribute__((address_space(1))) void gvoid;
typedef __attribute__((address_space(3))) void lvoid;

// async global->LDS, 16B per lane; LDS dest is wave-uniform base + lane*16
__device__ __forceinline__ void gl16(const u16* g, u16* l) {
    __builtin_amdgcn_global_load_lds((gvoid*)g, (lvoid*)l, 16, 0, 0);
}

__device__ __forceinline__ float4 ld4(const float* p) {
    return *reinterpret_cast<const float4*>(p);
}
__device__ __forceinline__ float sigf(float x) { return 1.f / (1.f + __expf(-x)); }
__device__ __forceinline__ float tanhfast(float x) { return 2.f / (1.f + __expf(-2.f * x)) - 1.f; }
__device__ __forceinline__ int gmap(int l, int s0, int CS) {
    int b = (unsigned)l / (unsigned)CS;
    return b * SQ + s0 + (l - b * CS);
}
__device__ __forceinline__ void st4h(u16* dst, float4 v) {
    _Float16 h0 = (_Float16)v.x, h1 = (_Float16)v.y, h2 = (_Float16)v.z, h3 = (_Float16)v.w;
    ushort4 u;
    u.x = *(u16*)&h0; u.y = *(u16*)&h1; u.z = *(u16*)&h2; u.w = *(u16*)&h3;
    *(ushort4*)dst = u;
}
__device__ __forceinline__ float h2f(u16 b) { _Float16 h; *(u16*)&h = b; return (float)h; }
__device__ __forceinline__ u16 f2h(float x) { _Float16 h = (_Float16)x; return *(u16*)&h; }

// pin a float4's components into VGPRs at this program point (forces the
// producing loads to complete here and prevents fold-forward)
#define KEEP4(v) asm volatile("" : "+v"(v.x), "+v"(v.y), "+v"(v.z), "+v"(v.w))
// component k (constant) of a float4 array, static-index safe under unroll
#define CBF(arr, k) ((((k) & 3) == 0) ? arr[(k) >> 2].x : \
                     (((k) & 3) == 1) ? arr[(k) >> 2].y : \
                     (((k) & 3) == 2) ? arr[(k) >> 2].z : arr[(k) >> 2].w)

// ---------------------------------------------------------------------------
// fp32 -> fp16 conversion (vec4)
// ---------------------------------------------------------------------------
__global__ __launch_bounds__(256) void cvt16(
    const float* __restrict__ s, u16* __restrict__ d, int n4)
{
    int i = blockIdx.x * 256 + threadIdx.x;
    if (i < n4) st4h(d + 4 * (size_t)i, ld4(s + 4 * (size_t)i));
}

// ---------------------------------------------------------------------------
// fused fp16 conversion of the 5 weight matrices (contiguous dst layout)
// ---------------------------------------------------------------------------
__global__ __launch_bounds__(256) void wcvt(
    const float* __restrict__ s0, const float* __restrict__ s1,
    const float* __restrict__ s2, const float* __restrict__ s3,
    const float* __restrict__ s4, u16* __restrict__ dst)
{
    int i = blockIdx.x * 256 + threadIdx.x;
    if (i >= 90112) return;
    const float* s; int off;
    if (i < 4096)       { s = s0; off = 0; }
    else if (i < 8192)  { s = s1; off = 4096; }
    else if (i < 24576) { s = s2; off = 8192; }
    else if (i < 40960) { s = s3; off = 24576; }
    else                { s = s4; off = 40960; }
    st4h(dst + 4 * (size_t)i, ld4(s + 4 * (size_t)(i - off)));
}

// ---------------------------------------------------------------------------
// Mk [50,128] fp32 -> Mkh [64,128] fp16, rows 50..63 zeroed
// ---------------------------------------------------------------------------
__global__ __launch_bounds__(256) void mkcvt(
    const float* __restrict__ Mk, u16* __restrict__ Mkh)
{
    int i = blockIdx.x * 256 + threadIdx.x;   // 2048 float4 slots
    if (i >= 64 * 32) return;
    int row = i >> 5;
    float4 v = (row < MM) ? ld4(Mk + (size_t)row * DQ + (i & 31) * 4)
                          : float4{0.f, 0.f, 0.f, 0.f};
    st4h(Mkh + 4 * (size_t)i, v);
}

// ---------------------------------------------------------------------------
// prep: Xp rows [0,Nc) = fp16(te+qe); rows [Nc,2Nc) = fp16(he+hte+ae+qe);
//       S3p = fp16(he+hte+ae); QEp = fp16(qe)
// ---------------------------------------------------------------------------
__global__ __launch_bounds__(256) void prep128(
    const int* __restrict__ q_data, const int* __restrict__ time_data,
    const int* __restrict__ attempt_data, const int* __restrict__ hint_data,
    const int* __restrict__ hintT_data,
    const float* __restrict__ q_emb, const float* __restrict__ time_emb,
    const float* __restrict__ attempt_emb, const float* __restrict__ ht_emb,
    u16* __restrict__ Xp, u16* __restrict__ S3p, u16* __restrict__ QEp,
    int s0, int CS, int Nc)
{
    int g = blockIdx.x * 256 + threadIdx.x;
    int l = g >> 5;
    int kq = (g & 31) << 2;
    if (l >= Nc) return;
    int n = gmap(l, s0, CS);
    float4 qe  = ld4(q_emb       + (size_t)q_data[n]       * DQ + kq);
    float4 te  = ld4(time_emb    + (size_t)time_data[n]    * DQ + kq);
    float4 ae  = ld4(attempt_emb + (size_t)attempt_data[n] * DQ + kq);
    float4 he  = ld4(ht_emb      + (size_t)hint_data[n]    * DQ + kq);
    float4 hte = ld4(ht_emb      + (size_t)hintT_data[n]   * DQ + kq);
    size_t off = (size_t)l * DQ + kq;
    float4 x1, s3, x2;
    x1.x = te.x + qe.x; x1.y = te.y + qe.y; x1.z = te.z + qe.z; x1.w = te.w + qe.w;
    s3.x = he.x + hte.x + ae.x; s3.y = he.y + hte.y + ae.y;
    s3.z = he.z + hte.z + ae.z; s3.w = he.w + hte.w + ae.w;
    x2.x = s3.x + qe.x; x2.y = s3.y + qe.y; x2.z = s3.z + qe.z; x2.w = s3.w + qe.w;
    st4h(Xp + off, x1);
    st4h(Xp + (size_t)Nc * DQ + off, x2);
    st4h(S3p + off, s3);
    st4h(QEp + off, qe);
}

// ---------------------------------------------------------------------------
// FUSED G1+G2 (R8-verified): Y2 = sig(tanh(X @ W1^T + b1) @ W2^T + b2),
// MODE-2 epilogue. T stays in LDS (swizzled layout).
// ---------------------------------------------------------------------------
__global__ __launch_bounds__(256, 2) void gemm12(
    const u16* __restrict__ A, const u16* __restrict__ W1h,
    const u16* __restrict__ W2h, const float* __restrict__ b1,
    const float* __restrict__ b2, u16* __restrict__ Yh,
    const u16* __restrict__ QEp, const u16* __restrict__ S3p, int Nc)
{
    __shared__ u16 smem[32768];          // 64KB: At 8192 | Bt 8192 | Tt 16384
    u16* At = smem;
    u16* Bt = smem + 8192;
    u16* Tt = smem + 16384;
    const int tid = threadIdx.x;
    const int row0 = blockIdx.x * 128;
    const int lane = tid & 63, wv = tid >> 6;
    const int wr = (wv >> 1) * 64, wc = (wv & 1) * 64;
    const int q = lane >> 4, c0 = lane & 15;

    floatx4 acc[4][4];
#pragma unroll
    for (int m = 0; m < 4; ++m)
#pragma unroll
        for (int n = 0; n < 4; ++n) acc[m][n] = (floatx4)0.f;

    // ---- GEMM1: X @ W1^T, K=128 ----
    for (int kt = 0; kt < 128; kt += 64) {
#pragma unroll
        for (int j = 0; j < 4; ++j) {
            int f = tid + j * 256; int r = f >> 3; int lg = (f & 7) ^ (r & 7);
            gl16(A + (size_t)(row0 + r) * 128 + kt + lg * 8, &At[f * 8]);
        }
#pragma unroll
        for (int j = 0; j < 4; ++j) {
            int f = tid + j * 256; int r = f >> 3; int lg = (f & 7) ^ (r & 7);
            gl16(W1h + (size_t)r * 128 + kt + lg * 8, &Bt[f * 8]);
        }
        __syncthreads();
#pragma unroll
        for (int kk = 0; kk < 2; ++kk) {
            half8 af[4], bf[4];
#pragma unroll
            for (int m = 0; m < 4; ++m) {
                int row = wr + m * 16 + c0;
                af[m] = *(half8*)&At[row * 64 + ((((kk << 2) | q)) ^ (row & 7)) * 8];
            }
#pragma unroll
            for (int n = 0; n < 4; ++n) {
                int row = wc + n * 16 + c0;
                bf[n] = *(half8*)&Bt[row * 64 + ((((kk << 2) | q)) ^ (row & 7)) * 8];
            }
#pragma unroll
            for (int m = 0; m < 4; ++m)
#pragma unroll
                for (int n = 0; n < 4; ++n)
                    acc[m][n] = __builtin_amdgcn_mfma_f32_16x16x32_f16(af[m], bf[n], acc[m][n], 0, 0, 0);
        }
        __syncthreads();
    }

    // ---- T = tanh(acc + b1) -> Tt (two swizzled [128][64] tiles) ----
    {
        float bv1[4];
#pragma unroll
        for (int n = 0; n < 4; ++n) bv1[n] = b1[wc + n * 16 + c0];
#pragma unroll
        for (int m = 0; m < 4; ++m)
#pragma unroll
            for (int r4 = 0; r4 < 4; ++r4) {
                int row = wr + m * 16 + q * 4 + r4;
#pragma unroll
                for (int n = 0; n < 4; ++n) {
                    int col = wc + n * 16 + c0;
                    float v = tanhfast(acc[m][n][r4] + bv1[n]);
                    int tile = col >> 6, cl = col & 63, gl = cl >> 3;
                    Tt[tile * 8192 + row * 64 + ((gl ^ (row & 7)) << 3) + (cl & 7)] = f2h(v);
                }
            }
    }
#pragma unroll
    for (int m = 0; m < 4; ++m)
#pragma unroll
        for (int n = 0; n < 4; ++n) acc[m][n] = (floatx4)0.f;

    // stage W2 kt=0 alongside T writes
#pragma unroll
    for (int j = 0; j < 4; ++j) {
        int f = tid + j * 256; int r = f >> 3; int lg = (f & 7) ^ (r & 7);
        gl16(W2h + (size_t)r * 128 + 0 + lg * 8, &Bt[f * 8]);
    }
    __syncthreads();

    // ---- GEMM2: T @ W2^T, K=128 (T resident in Tt) ----
#pragma unroll
    for (int kt = 0; kt < 2; ++kt) {
#pragma unroll
        for (int kk = 0; kk < 2; ++kk) {
            half8 af[4], bf[4];
#pragma unroll
            for (int m = 0; m < 4; ++m) {
                int row = wr + m * 16 + c0;
                af[m] = *(half8*)&Tt[kt * 8192 + row * 64 + ((((kk << 2) | q)) ^ (row & 7)) * 8];
            }
#pragma unroll
            for (int n = 0; n < 4; ++n) {
                int row = wc + n * 16 + c0;
                bf[n] = *(half8*)&Bt[row * 64 + ((((kk << 2) | q)) ^ (row & 7)) * 8];
            }
#pragma unroll
            for (int m = 0; m < 4; ++m)
#pragma unroll
                for (int n = 0; n < 4; ++n)
                    acc[m][n] = __builtin_amdgcn_mfma_f32_16x16x32_f16(af[m], bf[n], acc[m][n], 0, 0, 0);
        }
        if (kt == 0) {
            __syncthreads();
#pragma unroll
            for (int j = 0; j < 4; ++j) {
                int f = tid + j * 256; int r = f >> 3; int lg = (f & 7) ^ (r & 7);
                gl16(W2h + (size_t)r * 128 + 64 + lg * 8, &Bt[f * 8]);
            }
            __syncthreads();
        }
    }

    // ---- MODE-2 epilogue ----
    float bv[4];
#pragma unroll
    for (int n = 0; n < 4; ++n) bv[n] = b2[wc + n * 16 + c0];
#pragma unroll
    for (int m = 0; m < 4; ++m)
#pragma unroll
        for (int r4 = 0; r4 < 4; ++r4) {
            int row = row0 + wr + m * 16 + q * 4 + r4;
#pragma unroll
            for (int n = 0; n < 4; ++n) {
                int col = wc + n * 16 + c0;
                float v = sigf(acc[m][n][r4] + bv[n]);
                if (row < Nc) {
                    Yh[(size_t)row * 128 + col] = f2h(v);
                } else {
                    size_t o = (size_t)(row - Nc) * 128 + col;
                    float qe = h2f(QEp[o]), s3 = h2f(S3p[o]);
                    Yh[(size_t)row * 128 + col] = f2h(fmaf(v, s3, qe));
                }
            }
        }
}

// ---------------------------------------------------------------------------
// FUSED G3+wsoftmax (R8-verified): qp in LDS; ie -> RDIE; softmax -> Wb.
// ---------------------------------------------------------------------------
__global__ __launch_bounds__(256, 2) void gemm3w(
    const u16* __restrict__ X3, const u16* __restrict__ W1h,
    const float* __restrict__ b1, const u16* __restrict__ Mkh,
    const int* __restrict__ tidx, const float* __restrict__ temb,
    const u16* __restrict__ TF, u16* __restrict__ RDIE,
    float* __restrict__ Wb, int s0, int CS)
{
    __shared__ u16 smem[32768];          // At 8192 | Bt 8192 | Tt(qp) 16384
    u16* At = smem;
    u16* Bt = smem + 8192;
    u16* Tt = smem + 16384;
    const int tid = threadIdx.x;
    const int row0 = blockIdx.x * 128;
    const int lane = tid & 63, wv = tid >> 6;
    const int wr = (wv >> 1) * 64, wc = (wv & 1) * 64;
    const int q = lane >> 4, c0 = lane & 15;

    floatx4 acc[4][4];
#pragma unroll
    for (int m = 0; m < 4; ++m)
#pragma unroll
        for (int n = 0; n < 4; ++n) acc[m][n] = (floatx4)0.f;

    // ---- GEMM3: x3 @ W1^T, K=128 ----
    for (int kt = 0; kt < 128; kt += 64) {
#pragma unroll
        for (int j = 0; j < 4; ++j) {
            int f = tid + j * 256; int r = f >> 3; int lg = (f & 7) ^ (r & 7);
            gl16(X3 + (size_t)(row0 + r) * 128 + kt + lg * 8, &At[f * 8]);
        }
#pragma unroll
        for (int j = 0; j < 4; ++j) {
            int f = tid + j * 256; int r = f >> 3; int lg = (f & 7) ^ (r & 7);
            gl16(W1h + (size_t)r * 128 + kt + lg * 8, &Bt[f * 8]);
        }
        __syncthreads();
#pragma unroll
        for (int kk = 0; kk < 2; ++kk) {
            half8 af[4], bf[4];
#pragma unroll
            for (int m = 0; m < 4; ++m) {
                int row = wr + m * 16 + c0;
                af[m] = *(half8*)&At[row * 64 + ((((kk << 2) | q)) ^ (row & 7)) * 8];
            }
#pragma unroll
            for (int n = 0; n < 4; ++n) {
                int row = wc + n * 16 + c0;
                bf[n] = *(half8*)&Bt[row * 64 + ((((kk << 2) | q)) ^ (row & 7)) * 8];
            }
#pragma unroll
            for (int m = 0; m < 4; ++m)
#pragma unroll
                for (int n = 0; n < 4; ++n)
                    acc[m][n] = __builtin_amdgcn_mfma_f32_16x16x32_f16(af[m], bf[n], acc[m][n], 0, 0, 0);
        }
        __syncthreads();
    }

    // ---- qp = acc + b1 -> Tt (swizzled); ie = qp + tf*te -> RDIE ----
    {
        float bv1[4];
#pragma unroll
        for (int n = 0; n < 4; ++n) bv1[n] = b1[wc + n * 16 + c0];
#pragma unroll
        for (int m = 0; m < 4; ++m)
#pragma unroll
            for (int r4 = 0; r4 < 4; ++r4) {
                int rloc = wr + m * 16 + q * 4 + r4;
                int grow = row0 + rloc;
                int nmap = gmap(grow, s0, CS);
                const float* terow = temb + (size_t)tidx[nmap] * 128;
#pragma unroll
                for (int n = 0; n < 4; ++n) {
                    int col = wc + n * 16 + c0;
                    float qp = acc[m][n][r4] + bv1[n];
                    int tile = col >> 6, cl = col & 63, gl = cl >> 3;
                    Tt[tile * 8192 + rloc * 64 + ((gl ^ (rloc & 7)) << 3) + (cl & 7)] = f2h(qp);
                    float tf = h2f(TF[(size_t)grow * 128 + col]);
                    RDIE[(size_t)grow * 384 + 256 + col] = f2h(fmaf(tf, terow[col], qp));
                }
            }
    }
    // stage Mkh (both k-tiles, 16KB) into Bt
#pragma unroll
    for (int j = 0; j < 4; ++j) {
        int f = tid + j * 256;
        int fl = f & 511;
        int ktile = f >> 9;
        int r = fl >> 3;
        int lg = (fl & 7) ^ (r & 7);
        gl16(Mkh + (size_t)r * 128 + ktile * 64 + lg * 8, &Bt[f * 8]);
    }
    __syncthreads();

    // ---- logits = qp @ Mkh^T ----
    const int wrW = wv * 32;
    floatx4 acc2[2][4];
#pragma unroll
    for (int m = 0; m < 2; ++m)
#pragma unroll
        for (int n = 0; n < 4; ++n) acc2[m][n] = (floatx4)0.f;
#pragma unroll
    for (int kt = 0; kt < 2; ++kt)
#pragma unroll
        for (int kk = 0; kk < 2; ++kk) {
            half8 af[2], bf[4];
#pragma unroll
            for (int m = 0; m < 2; ++m) {
                int row = wrW + m * 16 + c0;
                af[m] = *(half8*)&Tt[kt * 8192 + row * 64 + ((((kk << 2) | q)) ^ (row & 7)) * 8];
            }
#pragma unroll
            for (int n = 0; n < 4; ++n) {
                int row = n * 16 + c0;
                bf[n] = *(half8*)&Bt[kt * 4096 + row * 64 + ((((kk << 2) | q)) ^ (row & 7)) * 8];
            }
#pragma unroll
            for (int m = 0; m < 2; ++m)
#pragma unroll
                for (int n = 0; n < 4; ++n)
                    acc2[m][n] = __builtin_amdgcn_mfma_f32_16x16x32_f16(af[m], bf[n], acc2[m][n], 0, 0, 0);
        }
    __syncthreads();

    // ---- softmax ----
    float* Sred = (float*)smem;
#pragma unroll
    for (int m = 0; m < 2; ++m)
#pragma unroll
        for (int r4 = 0; r4 < 4; ++r4) {
            int row = wrW + m * 16 + q * 4 + r4;
#pragma unroll
            for (int n = 0; n < 4; ++n)
                Sred[row * 67 + n * 16 + c0] = acc2[m][n][r4];
        }
    __syncthreads();

    if (tid < 128) {
        float* s = &Sred[tid * 67];
        float mx = -3.0e38f;
#pragma unroll
        for (int m = 0; m < MM; ++m) mx = fmaxf(mx, s[m]);
        float sum = 0.f;
#pragma unroll
        for (int m = 0; m < MM; ++m) { float e = __expf(s[m] - mx); s[m] = e; sum += e; }
        float inv = 1.f / sum;
#pragma unroll
        for (int m = 0; m < MM; ++m) s[m] *= inv;
        s[50] = 0.f; s[51] = 0.f;
    }
    __syncthreads();

    for (int i = tid; i < 128 * 13; i += 256) {
        int row = i / 13, seg = i - row * 13;
        float4 v;
        v.x = Sred[row * 67 + seg * 4 + 0];
        v.y = Sred[row * 67 + seg * 4 + 1];
        v.z = Sred[row * 67 + seg * 4 + 2];
        v.w = Sred[row * 67 + seg * 4 + 3];
        *(float4*)(Wb + (size_t)(row0 + row) * WSTRIDE + seg * 4) = v;
    }
}

// ---------------------------------------------------------------------------
// fp16 MFMA GEMM (MODE 4 EAtab build, MODE 5 readout), BK=64,
// global_load_lds staging with XOR-granule swizzle (R7-verified).
// Grid is dim3(4, rows/128): the 4 col-group blocks of a row-block dispatch
// ADJACENTLY (temporal locality -> A-tile re-reads hit L2/L3, not HBM).
// launch_bounds (256,4): 4 blocks/CU (32KB LDS x4 = 128KB, VGPR<=128).
// ---------------------------------------------------------------------------
template <int MODE>
__global__ __launch_bounds__(256, 4) void gemm16(
    const u16* __restrict__ A, const u16* __restrict__ W0,
    const u16* __restrict__ W1, const float* __restrict__ b0,
    const float* __restrict__ b1, u16* __restrict__ Yh,
    float* __restrict__ Yf,
    u16* __restrict__ AUX, const float* __restrict__ predW,
    int K)
{
    __shared__ u16 smem[2 * 128 * 64];   // 32768 B
    u16* At = smem;
    u16* Bt = smem + 128 * 64;
    const int tid = threadIdx.x;
    const int row0 = blockIdx.y * 128;
    const int by = blockIdx.x;

    const u16* Wp;
    int col0;
    if constexpr (MODE == 4) { Wp = (by < 2) ? W0 : W1; col0 = (by & 1) * 128; }
    else { Wp = W0; col0 = by * 128; }
    const float* bias = (MODE == 4 && by >= 2) ? b1 : b0;

    floatx4 acc[4][4];
#pragma unroll
    for (int m = 0; m < 4; ++m)
#pragma unroll
        for (int n = 0; n < 4; ++n) acc[m][n] = (floatx4)0.f;

    const int lane = tid & 63, wv = tid >> 6;
    const int wr = (wv >> 1) * 64, wc = (wv & 1) * 64;
    const int q = lane >> 4, c0 = lane & 15;

    for (int kt = 0; kt < K; kt += 64) {
#pragma unroll
        for (int j = 0; j < 4; ++j) {
            int f = tid + j * 256;
            int r = f >> 3;
            int lg = (f & 7) ^ (r & 7);
            gl16(A + (size_t)(row0 + r) * K + kt + lg * 8, &At[f * 8]);
        }
#pragma unroll
        for (int j = 0; j < 4; ++j) {
            int f = tid + j * 256;
            int r = f >> 3;
            int lg = (f & 7) ^ (r & 7);
            gl16(Wp + (size_t)(col0 + r) * K + kt + lg * 8, &Bt[f * 8]);
        }
        __syncthreads();
#pragma unroll
        for (int kk = 0; kk < 2; ++kk) {
            half8 af[4], bf[4];
#pragma unroll
            for (int m = 0; m < 4; ++m) {
                int row = wr + m * 16 + c0;
                af[m] = *(half8*)&At[row * 64 + ((((kk << 2) | q)) ^ (row & 7)) * 8];
            }
#pragma unroll
            for (int n = 0; n < 4; ++n) {
                int row = wc + n * 16 + c0;
                bf[n] = *(half8*)&Bt[row * 64 + ((((kk << 2) | q)) ^ (row & 7)) * 8];
            }
#pragma unroll
            for (int m = 0; m < 4; ++m)
#pragma unroll
                for (int n = 0; n < 4; ++n)
                    acc[m][n] = __builtin_amdgcn_mfma_f32_16x16x32_f16(af[m], bf[n], acc[m][n], 0, 0, 0);
        }
        __syncthreads();
    }

    float bv[4];
#pragma unroll
    for (int n = 0; n < 4; ++n) bv[n] = bias[col0 + wc + n * 16 + c0];

    if constexpr (MODE == 5) {
        float pw[4];
#pragma unroll
        for (int n = 0; n < 4; ++n) pw[n] = predW[col0 + wc + n * 16 + c0];
        float* red = (float*)smem;          // [128][33] = 16896 B
#pragma unroll
        for (int m = 0; m < 4; ++m)
#pragma unroll
            for (int r4 = 0; r4 < 4; ++r4) {
                int row = wr + m * 16 + q * 4 + r4;
                float pp = 0.f;
#pragma unroll
                for (int n = 0; n < 4; ++n)
                    pp = fmaf(tanhfast(acc[m][n][r4] + bv[n]), pw[n], pp);
                red[row * 33 + (wv & 1) * 16 + c0] = pp;
            }
        __syncthreads();
        if (tid < 128) {
            float s = 0.f;
#pragma unroll
            for (int j = 0; j < 32; ++j) s += red[tid * 33 + j];
            atomicAdd(&Yf[row0 + tid], s);
        }
    } else { // MODE 4
#pragma unroll
        for (int m = 0; m < 4; ++m)
#pragma unroll
            for (int r4 = 0; r4 < 4; ++r4) {
                int row = row0 + wr + m * 16 + q * 4 + r4;
#pragma unroll
                for (int n = 0; n < 4; ++n) {
                    int col = col0 + wc + n * 16 + c0;
                    float v = acc[m][n][r4] + bv[n];
                    bool isE = (by < 2);
                    v = isE ? sigf(v) : tanhfast(v);
                    AUX[((size_t)row * 256 + col) * 2 + (isE ? 0 : 1)] = f2h(v);
                }
            }
    }
}

// ---------------------------------------------------------------------------
// DKVMN scan v10: v9 + REAL register double-buffer. v9's wpp[2][13] was
// silently DCE'd (VGPR=104 < banks alone) — compiler folded the prefetch
// loads into uses, exposing full LDS latency per step. v10 pins the next-
// step bank into VGPRs with asm-use (KEEP4) placed AFTER the current step's
// compute: loads issue early, the lgkmcnt wait lands post-compute, values
// can't fold forward. Expected VGPR ~170-200 (1 block/CU -> budget free).
// ---------------------------------------------------------------------------
__global__ __launch_bounds__(256, 1) void scan_kernel(
    const float* __restrict__ Wb, const int* __restrict__ qa_data,
    const u32* __restrict__ EAtab,
    const float* __restrict__ Mv0, float* __restrict__ MvSt,
    u16* __restrict__ RDIE, int CS, int s0, int first)
{
    __shared__ float wt[2][WT * WSTRIDE];   // 2 x 520 floats = 4160 B
    const int b = blockIdx.x;
    const int d = threadIdx.x;

    f2 mv[25];
    if (first) {
#pragma unroll
        for (int j = 0; j < 25; ++j) {
            mv[j].x = Mv0[(2 * j) * DV + d];
            mv[j].y = Mv0[(2 * j + 1) * DV + d];
        }
    } else {
#pragma unroll
        for (int j = 0; j < 25; ++j) {
            mv[j].x = MvSt[((size_t)b * MM + 2 * j) * DV + d];
            mv[j].y = MvSt[((size_t)b * MM + 2 * j + 1) * DV + d];
        }
    }

    const float* wbase = Wb + (size_t)b * CS * WSTRIDE;   // rows contiguous
    const int* qap = qa_data + (size_t)b * SQ + s0;
    u16* rp = RDIE + (size_t)b * CS * 384 + d;

    const int NT = CS / WT;
    const bool loader = (d < (WT * WSTRIDE / 4));   // 130 loader threads

    // Preload tile 0: W -> LDS buf0, ea -> regs (index then gather)
    if (loader) *(float4*)&wt[0][d * 4] = ld4(wbase + d * 4);
    u32 ea[WT];
    {
        int qi[WT];
#pragma unroll
        for (int i = 0; i < WT; ++i) qi[i] = qap[i];
#pragma unroll
        for (int i = 0; i < WT; ++i) ea[i] = EAtab[(size_t)qi[i] * DV + d];
    }
    __syncthreads();

    int cur = 0;
    for (int tile = 0; tile < NT; ++tile) {
        // Prefetch next tile (global -> regs); consumed after this tile
        float4 wreg;
        u32 ean[WT];
        const bool havenext = (tile + 1 < NT);
        if (havenext) {
            if (loader) wreg = ld4(wbase + (size_t)(tile + 1) * WT * WSTRIDE + d * 4);
            int qn[WT];
#pragma unroll
            for (int i = 0; i < WT; ++i) qn[i] = qap[(tile + 1) * WT + i];
#pragma unroll
            for (int i = 0; i < WT; ++i) ean[i] = EAtab[(size_t)qn[i] * DV + d];
        }

        // load step 0 into current bank and PIN it
        float4 cb[13], nb[13];
#pragma unroll
        for (int i = 0; i < 13; ++i) cb[i] = *(const float4*)&wt[cur][i * 4];
#pragma unroll
        for (int i = 0; i < 13; ++i) KEEP4(cb[i]);

#pragma unroll
        for (int s = 0; s < WT; ++s) {
            // issue step s+1's broadcast ds_reads (not yet waited on)
            if (s + 1 < WT) {
#pragma unroll
                for (int i = 0; i < 13; ++i)
                    nb[i] = *(const float4*)&wt[cur][(s + 1) * WSTRIDE + i * 4];
            }
            // compute step s from the pinned bank
            u32 eav = ea[s];
            float e = h2f((u16)(eav & 0xffff));
            float a = h2f((u16)(eav >> 16));
            f2 e2; e2.x = e; e2.y = e;
            f2 a2; a2.x = a; a2.y = a;
            f2 r0 = (f2)0.f, r1 = (f2)0.f, r2 = (f2)0.f, r3 = (f2)0.f;
#pragma unroll
            for (int j = 0; j < 25; ++j) {
                f2 w2;
                w2.x = CBF(cb, 2 * j);
                w2.y = CBF(cb, 2 * j + 1);
                if ((j & 3) == 0)      r0 += w2 * mv[j];
                else if ((j & 3) == 1) r1 += w2 * mv[j];
                else if ((j & 3) == 2) r2 += w2 * mv[j];
                else                   r3 += w2 * mv[j];
                f2 tt = a2 - e2 * mv[j];
                mv[j] += w2 * tt;
            }
            f2 rs = (r0 + r1) + (r2 + r3);
            rp[(size_t)(tile * WT + s) * 384] = f2h(rs.x + rs.y);
            // pin next bank AFTER compute (wait lands here), rotate banks
            if (s + 1 < WT) {
#pragma unroll
                for (int i = 0; i < 13; ++i) KEEP4(nb[i]);
#pragma unroll
                for (int i = 0; i < 13; ++i) cb[i] = nb[i];
            }
        }

        if (havenext) {
            if (loader) *(float4*)&wt[1 - cur][d * 4] = wreg;
#pragma unroll
            for (int i = 0; i < WT; ++i) ea[i] = ean[i];
            __syncthreads();
            cur ^= 1;
        }
    }

#pragma unroll
    for (int j = 0; j < 25; ++j) {
        MvSt[((size_t)b * MM + 2 * j) * DV + d]     = mv[j].x;
        MvSt[((size_t)b * MM + 2 * j + 1) * DV + d] = mv[j].y;
    }
}

// ---------------------------------------------------------------------------
// loss + outputs
// ---------------------------------------------------------------------------
__global__ __launch_bounds__(256) void loss_part(
    const float* __restrict__ P, const int* __restrict__ target,
    const float* __restrict__ pred_b, float* __restrict__ out,
    float* __restrict__ R2, int s0, int CS, int Nc)
{
    int l = blockIdx.x * 256 + threadIdx.x;
    float le = 0.f, mf = 0.f;
    if (l < Nc) {
        int n = gmap(l, s0, CS);
        float p = P[l] + pred_b[0];
        int t = target[n];
        float y = (t >= 1) ? (float)(t - 1) : 0.f;
        float sig = 1.f / (1.f + __expf(-p));
        if (t >= 1) {
            mf = 1.f;
            le = fmaxf(p, 0.f) + log1pf(__expf(-fabsf(p))) - p * y;
        }
        out[1 + n] = sig * mf;
        out[1 + NROWS + n] = y * mf;
    }
#pragma unroll
    for (int off = 32; off; off >>= 1) {
        le += __shfl_down(le, off);
        mf += __shfl_down(mf, off);
    }
    __shared__ float sl[4], sm[4];
    int wid = threadIdx.x >> 6;
    if ((threadIdx.x & 63) == 0) { sl[wid] = le; sm[wid] = mf; }
    __syncthreads();
    if (threadIdx.x == 0) {
        atomicAdd(R2, sl[0] + sl[1] + sl[2] + sl[3]);
        atomicAdd(R2 + 1, sm[0] + sm[1] + sm[2] + sm[3]);
    }
}

__global__ void loss_fin(const float* __restrict__ R2, float* __restrict__ out)
{
    out[0] = R2[0] / fmaxf(R2[1], 1.f);
}

// ---------------------------------------------------------------------------
extern "C" void kernel_launch(void* const* d_in, const int* in_sizes, int n_in,
                              void* d_out, int out_size, void* d_ws, size_t ws_size,
                              hipStream_t stream)
{
    const int* q_data       = (const int*)d_in[0];
    const int* qa_data      = (const int*)d_in[1];
    const int* target       = (const int*)d_in[2];
    const int* time_data    = (const int*)d_in[3];
    const int* attempt_data = (const int*)d_in[4];
    const int* hint_data    = (const int*)d_in[5];
    const int* hintT_data   = (const int*)d_in[6];
    const float* q_emb    = (const float*)d_in[7];
    const float* qa_emb   = (const float*)d_in[8];
    const float* time_emb = (const float*)d_in[9];
    const float* att_emb  = (const float*)d_in[10];
    const float* ht_emb   = (const float*)d_in[11];
    const float* Mk       = (const float*)d_in[12];
    const float* Mv0      = (const float*)d_in[13];
    const float* diff_W   = (const float*)d_in[14];
    const float* diff_b   = (const float*)d_in[15];
    const float* diff2_W  = (const float*)d_in[16];
    const float* diff2_b  = (const float*)d_in[17];
    const float* erase_W  = (const float*)d_in[18];
    const float* erase_b  = (const float*)d_in[19];
    const float* add_W    = (const float*)d_in[20];
    const float* add_b    = (const float*)d_in[21];
    const float* read_W   = (const float*)d_in[22];
    const float* read_b   = (const float*)d_in[23];
    const float* pred_W   = (const float*)d_in[24];
    const float* pred_b   = (const float*)d_in[25];
    float* out = (float*)d_out;
    (void)in_sizes; (void)n_in; (void)out_size;

    // Adaptive chunking over S (CS must be divisible by WT=10).
    static const int cs_opts[] = {500, 250, 100, 50, 20, 10};
    const size_t FIXED = 44700000ull;
    int CS = 0;
    for (int i = 0; i < 6; ++i) {
        size_t need = (size_t)NB * cs_opts[i] * 2016ull + FIXED;
        if (need <= ws_size) { CS = cs_opts[i]; break; }
    }
    if (CS == 0) return;
    const int NCH = SQ / CS;
    const int Nc = NB * CS;

    // Workspace layout (16B-aligned sections)
    float* MvSt  = (float*)d_ws;                         // [NB*MM*DV]
    float* wbuf  = MvSt + (size_t)NB * MM * DV;          // [Nc*52]
    float* bufP  = wbuf + (size_t)Nc * WSTRIDE;          // [Nc]
    float* bufR2 = bufP + Nc;                            // [4]
    u16*  Xp     = (u16*)(bufR2 + 4);                    // [2Nc*128]
    u16*  S3p    = Xp + (size_t)2 * Nc * 128;            // [Nc*128]
    u16*  QEp    = S3p + (size_t)Nc * 128;               // [Nc*128]
    u16*  RDIE   = QEp + (size_t)Nc * 128;               // [Nc*384]
    u16*  dWh    = RDIE + (size_t)Nc * 384;              // 16384
    u16*  d2Wh   = dWh + 16384;                          // 16384
    u16*  eWh    = d2Wh + 16384;                         // 65536
    u16*  aWh    = eWh + 65536;                          // 65536
    u16*  rWh    = aWh + 65536;                          // 196608
    u16*  qaEh   = rWh + 196608;                         // 5,120,256
    u16*  Mkh    = qaEh + 5120256;                       // 8,192 (64x128)
    u32*  EAtab  = (u32*)(Mkh + 8192);                   // [NQA*256] u32 = 20.6 MB

    // Fused one-time weight conversions (5 matrices -> contiguous dWh..rWh)
    wcvt<<<352, 256, 0, stream>>>(diff_W, diff2_W, erase_W, add_W, read_W, dWh);
    cvt16<<<5001, 256, 0, stream>>>(qa_emb, qaEh, 5120256 / 4);
    mkcvt<<<8, 256, 0, stream>>>(Mk, Mkh);
    hipMemsetAsync(bufR2, 0, 4 * sizeof(float), stream);

    // One-time e/a gate TABLE over all distinct qa indices (NQA rows)
    gemm16<4><<<dim3(4, NQA / 128), 256, 0, stream>>>(
        qaEh, eWh, aWh, erase_b, add_b, nullptr, nullptr,
        (u16*)EAtab, nullptr, 256);

    for (int c = 0; c < NCH; ++c) {
        const int s0 = c * CS;

        prep128<<<Nc / 8, 256, 0, stream>>>(
            q_data, time_data, attempt_data, hint_data, hintT_data,
            q_emb, time_emb, att_emb, ht_emb, Xp, S3p, QEp, s0, CS, Nc);

        // FUSED G1+G2: tf (rows<Nc) and x3 (rows>=Nc) in one pass
        gemm12<<<2 * Nc / 128, 256, 0, stream>>>(
            Xp, dWh, d2Wh, diff_b, diff2_b, Xp, QEp, S3p, Nc);

        // FUSED G3+wsoftmax: qp in LDS; ie -> RDIE; w -> wbuf
        gemm3w<<<Nc / 128, 256, 0, stream>>>(
            Xp + (size_t)Nc * 128, dWh, diff_b, Mkh,
            time_data, time_emb, Xp, RDIE, wbuf, s0, CS);

        // scan -> RD fp16 into RDIE[:,0:256); e/a gathered from EAtab
        scan_kernel<<<NB, DV, 0, stream>>>(
            wbuf, qa_data, EAtab, Mv0, MvSt, RDIE, CS, s0, c == 0 ? 1 : 0);

        hipMemsetAsync(bufP, 0, (size_t)Nc * sizeof(float), stream);
        // G5: rc = tanh([rd|ie] @ read_W^T + b); pred partials -> bufP
        gemm16<5><<<dim3(4, Nc / 128), 256, 0, stream>>>(
            RDIE, rWh, nullptr, read_b, nullptr, nullptr, bufP,
            nullptr, pred_W, 384);

        loss_part<<<Nc / 256, 256, 0, stream>>>(bufP, target, pred_b, out, bufR2, s0, CS, Nc);
    }

    loss_fin<<<1, 1, 0, stream>>>(bufR2, out);
}

// Round 11
// 610.536 us; speedup vs baseline: 1.0857x; 1.0857x over previous
//
#include <hip/hip_runtime.h>
#include <cstdint>
#include <cstddef>

// Problem constants
#define NB 256
#define SQ 500
#define NROWS (NB * SQ)   // 128000
#define DQ 128
#define DV 256
#define MM 50
#define FF 512
#define NQA 20096         // padded distinct qa indices (2*NQ+1 = 20001 -> 157*128)
#define WSTRIDE 52        // padded w-row stride (16B aligned)
#define WT 10             // scan LDS tile: steps per stage

typedef _Float16 half8 __attribute__((ext_vector_type(8)));
typedef float floatx4 __attribute__((ext_vector_type(4)));
typedef float f2 __attribute__((ext_vector_type(2)));
typedef unsigned int u32;
typedef unsigned short u16;

typedef __attribute__((address_space(1))) void gvoid;
typedef __attribute__((address_space(3))) void lvoid;

// async global->LDS, 16B per lane; LDS dest is wave-uniform base + lane*16
__device__ __forceinline__ void gl16(const u16* g, u16* l) {
    __builtin_amdgcn_global_load_lds((gvoid*)g, (lvoid*)l, 16, 0, 0);
}

__device__ __forceinline__ float4 ld4(const float* p) {
    return *reinterpret_cast<const float4*>(p);
}
__device__ __forceinline__ float sigf(float x) { return 1.f / (1.f + __expf(-x)); }
__device__ __forceinline__ float tanhfast(float x) { return 2.f / (1.f + __expf(-2.f * x)) - 1.f; }
__device__ __forceinline__ int gmap(int l, int s0, int CS) {
    int b = (unsigned)l / (unsigned)CS;
    return b * SQ + s0 + (l - b * CS);
}
__device__ __forceinline__ void st4h(u16* dst, float4 v) {
    _Float16 h0 = (_Float16)v.x, h1 = (_Float16)v.y, h2 = (_Float16)v.z, h3 = (_Float16)v.w;
    ushort4 u;
    u.x = *(u16*)&h0; u.y = *(u16*)&h1; u.z = *(u16*)&h2; u.w = *(u16*)&h3;
    *(ushort4*)dst = u;
}
__device__ __forceinline__ float h2f(u16 b) { _Float16 h; *(u16*)&h = b; return (float)h; }
__device__ __forceinline__ u16 f2h(float x) { _Float16 h = (_Float16)x; return *(u16*)&h; }

// ---------------------------------------------------------------------------
// fp32 -> fp16 conversion (vec4)
// ---------------------------------------------------------------------------
__global__ __launch_bounds__(256) void cvt16(
    const float* __restrict__ s, u16* __restrict__ d, int n4)
{
    int i = blockIdx.x * 256 + threadIdx.x;
    if (i < n4) st4h(d + 4 * (size_t)i, ld4(s + 4 * (size_t)i));
}

// ---------------------------------------------------------------------------
// fused fp16 conversion of the 5 weight matrices (contiguous dst layout)
// ---------------------------------------------------------------------------
__global__ __launch_bounds__(256) void wcvt(
    const float* __restrict__ s0, const float* __restrict__ s1,
    const float* __restrict__ s2, const float* __restrict__ s3,
    const float* __restrict__ s4, u16* __restrict__ dst)
{
    int i = blockIdx.x * 256 + threadIdx.x;
    if (i >= 90112) return;
    const float* s; int off;
    if (i < 4096)       { s = s0; off = 0; }
    else if (i < 8192)  { s = s1; off = 4096; }
    else if (i < 24576) { s = s2; off = 8192; }
    else if (i < 40960) { s = s3; off = 24576; }
    else                { s = s4; off = 40960; }
    st4h(dst + 4 * (size_t)i, ld4(s + 4 * (size_t)(i - off)));
}

// ---------------------------------------------------------------------------
// Mk [50,128] fp32 -> Mkh [64,128] fp16, rows 50..63 zeroed
// ---------------------------------------------------------------------------
__global__ __launch_bounds__(256) void mkcvt(
    const float* __restrict__ Mk, u16* __restrict__ Mkh)
{
    int i = blockIdx.x * 256 + threadIdx.x;   // 2048 float4 slots
    if (i >= 64 * 32) return;
    int row = i >> 5;
    float4 v = (row < MM) ? ld4(Mk + (size_t)row * DQ + (i & 31) * 4)
                          : float4{0.f, 0.f, 0.f, 0.f};
    st4h(Mkh + 4 * (size_t)i, v);
}

// ---------------------------------------------------------------------------
// prep: Xp rows [0,Nc) = fp16(te+qe); rows [Nc,2Nc) = fp16(he+hte+ae+qe);
// qe -> RDIE[l*384 + 0:128), s3 -> RDIE[l*384 + 128:256)   (aliased region:
// consumed by gemm12's epilogue, later overwritten by the scan's rd)
// ---------------------------------------------------------------------------
__global__ __launch_bounds__(256) void prep128(
    const int* __restrict__ q_data, const int* __restrict__ time_data,
    const int* __restrict__ attempt_data, const int* __restrict__ hint_data,
    const int* __restrict__ hintT_data,
    const float* __restrict__ q_emb, const float* __restrict__ time_emb,
    const float* __restrict__ attempt_emb, const float* __restrict__ ht_emb,
    u16* __restrict__ Xp, u16* __restrict__ RDIE,
    int s0, int CS, int Nc)
{
    int g = blockIdx.x * 256 + threadIdx.x;
    int l = g >> 5;
    int kq = (g & 31) << 2;
    if (l >= Nc) return;
    int n = gmap(l, s0, CS);
    float4 qe  = ld4(q_emb       + (size_t)q_data[n]       * DQ + kq);
    float4 te  = ld4(time_emb    + (size_t)time_data[n]    * DQ + kq);
    float4 ae  = ld4(attempt_emb + (size_t)attempt_data[n] * DQ + kq);
    float4 he  = ld4(ht_emb      + (size_t)hint_data[n]    * DQ + kq);
    float4 hte = ld4(ht_emb      + (size_t)hintT_data[n]   * DQ + kq);
    size_t off = (size_t)l * DQ + kq;
    float4 x1, s3, x2;
    x1.x = te.x + qe.x; x1.y = te.y + qe.y; x1.z = te.z + qe.z; x1.w = te.w + qe.w;
    s3.x = he.x + hte.x + ae.x; s3.y = he.y + hte.y + ae.y;
    s3.z = he.z + hte.z + ae.z; s3.w = he.w + hte.w + ae.w;
    x2.x = s3.x + qe.x; x2.y = s3.y + qe.y; x2.z = s3.z + qe.z; x2.w = s3.w + qe.w;
    st4h(Xp + off, x1);
    st4h(Xp + (size_t)Nc * DQ + off, x2);
    st4h(RDIE + (size_t)l * 384 + kq, qe);
    st4h(RDIE + (size_t)l * 384 + 128 + kq, s3);
}

// ---------------------------------------------------------------------------
// FUSED G1+G2 (R8-verified): Y2 = sig(tanh(X @ W1^T + b1) @ W2^T + b2),
// MODE-2 epilogue (qe/s3 read from the aliased RDIE region, stride 384).
// ---------------------------------------------------------------------------
__global__ __launch_bounds__(256, 2) void gemm12(
    const u16* __restrict__ A, const u16* __restrict__ W1h,
    const u16* __restrict__ W2h, const float* __restrict__ b1,
    const float* __restrict__ b2, u16* __restrict__ Yh,
    const u16* __restrict__ RDIE, int Nc)
{
    __shared__ u16 smem[32768];          // 64KB: At 8192 | Bt 8192 | Tt 16384
    u16* At = smem;
    u16* Bt = smem + 8192;
    u16* Tt = smem + 16384;
    const int tid = threadIdx.x;
    const int row0 = blockIdx.x * 128;
    const int lane = tid & 63, wv = tid >> 6;
    const int wr = (wv >> 1) * 64, wc = (wv & 1) * 64;
    const int q = lane >> 4, c0 = lane & 15;

    floatx4 acc[4][4];
#pragma unroll
    for (int m = 0; m < 4; ++m)
#pragma unroll
        for (int n = 0; n < 4; ++n) acc[m][n] = (floatx4)0.f;

    // ---- GEMM1: X @ W1^T, K=128 ----
    for (int kt = 0; kt < 128; kt += 64) {
#pragma unroll
        for (int j = 0; j < 4; ++j) {
            int f = tid + j * 256; int r = f >> 3; int lg = (f & 7) ^ (r & 7);
            gl16(A + (size_t)(row0 + r) * 128 + kt + lg * 8, &At[f * 8]);
        }
#pragma unroll
        for (int j = 0; j < 4; ++j) {
            int f = tid + j * 256; int r = f >> 3; int lg = (f & 7) ^ (r & 7);
            gl16(W1h + (size_t)r * 128 + kt + lg * 8, &Bt[f * 8]);
        }
        __syncthreads();
#pragma unroll
        for (int kk = 0; kk < 2; ++kk) {
            half8 af[4], bf[4];
#pragma unroll
            for (int m = 0; m < 4; ++m) {
                int row = wr + m * 16 + c0;
                af[m] = *(half8*)&At[row * 64 + ((((kk << 2) | q)) ^ (row & 7)) * 8];
            }
#pragma unroll
            for (int n = 0; n < 4; ++n) {
                int row = wc + n * 16 + c0;
                bf[n] = *(half8*)&Bt[row * 64 + ((((kk << 2) | q)) ^ (row & 7)) * 8];
            }
#pragma unroll
            for (int m = 0; m < 4; ++m)
#pragma unroll
                for (int n = 0; n < 4; ++n)
                    acc[m][n] = __builtin_amdgcn_mfma_f32_16x16x32_f16(af[m], bf[n], acc[m][n], 0, 0, 0);
        }
        __syncthreads();
    }

    // ---- T = tanh(acc + b1) -> Tt (two swizzled [128][64] tiles) ----
    {
        float bv1[4];
#pragma unroll
        for (int n = 0; n < 4; ++n) bv1[n] = b1[wc + n * 16 + c0];
#pragma unroll
        for (int m = 0; m < 4; ++m)
#pragma unroll
            for (int r4 = 0; r4 < 4; ++r4) {
                int row = wr + m * 16 + q * 4 + r4;
#pragma unroll
                for (int n = 0; n < 4; ++n) {
                    int col = wc + n * 16 + c0;
                    float v = tanhfast(acc[m][n][r4] + bv1[n]);
                    int tile = col >> 6, cl = col & 63, gl = cl >> 3;
                    Tt[tile * 8192 + row * 64 + ((gl ^ (row & 7)) << 3) + (cl & 7)] = f2h(v);
                }
            }
    }
#pragma unroll
    for (int m = 0; m < 4; ++m)
#pragma unroll
        for (int n = 0; n < 4; ++n) acc[m][n] = (floatx4)0.f;

    // stage W2 kt=0 alongside T writes
#pragma unroll
    for (int j = 0; j < 4; ++j) {
        int f = tid + j * 256; int r = f >> 3; int lg = (f & 7) ^ (r & 7);
        gl16(W2h + (size_t)r * 128 + 0 + lg * 8, &Bt[f * 8]);
    }
    __syncthreads();

    // ---- GEMM2: T @ W2^T, K=128 (T resident in Tt) ----
#pragma unroll
    for (int kt = 0; kt < 2; ++kt) {
#pragma unroll
        for (int kk = 0; kk < 2; ++kk) {
            half8 af[4], bf[4];
#pragma unroll
            for (int m = 0; m < 4; ++m) {
                int row = wr + m * 16 + c0;
                af[m] = *(half8*)&Tt[kt * 8192 + row * 64 + ((((kk << 2) | q)) ^ (row & 7)) * 8];
            }
#pragma unroll
            for (int n = 0; n < 4; ++n) {
                int row = wc + n * 16 + c0;
                bf[n] = *(half8*)&Bt[row * 64 + ((((kk << 2) | q)) ^ (row & 7)) * 8];
            }
#pragma unroll
            for (int m = 0; m < 4; ++m)
#pragma unroll
                for (int n = 0; n < 4; ++n)
                    acc[m][n] = __builtin_amdgcn_mfma_f32_16x16x32_f16(af[m], bf[n], acc[m][n], 0, 0, 0);
        }
        if (kt == 0) {
            __syncthreads();
#pragma unroll
            for (int j = 0; j < 4; ++j) {
                int f = tid + j * 256; int r = f >> 3; int lg = (f & 7) ^ (r & 7);
                gl16(W2h + (size_t)r * 128 + 64 + lg * 8, &Bt[f * 8]);
            }
            __syncthreads();
        }
    }

    // ---- MODE-2 epilogue (qe/s3 from aliased RDIE, stride 384) ----
    float bv[4];
#pragma unroll
    for (int n = 0; n < 4; ++n) bv[n] = b2[wc + n * 16 + c0];
#pragma unroll
    for (int m = 0; m < 4; ++m)
#pragma unroll
        for (int r4 = 0; r4 < 4; ++r4) {
            int row = row0 + wr + m * 16 + q * 4 + r4;
#pragma unroll
            for (int n = 0; n < 4; ++n) {
                int col = wc + n * 16 + c0;
                float v = sigf(acc[m][n][r4] + bv[n]);
                if (row < Nc) {
                    Yh[(size_t)row * 128 + col] = f2h(v);
                } else {
                    size_t o = (size_t)(row - Nc) * 384 + col;
                    float qe = h2f(RDIE[o]), s3 = h2f(RDIE[o + 128]);
                    Yh[(size_t)row * 128 + col] = f2h(fmaf(v, s3, qe));
                }
            }
        }
}

// ---------------------------------------------------------------------------
// FUSED G3+wsoftmax (R8-verified): qp in LDS; ie -> RDIE; softmax -> Wb.
// ---------------------------------------------------------------------------
__global__ __launch_bounds__(256, 2) void gemm3w(
    const u16* __restrict__ X3, const u16* __restrict__ W1h,
    const float* __restrict__ b1, const u16* __restrict__ Mkh,
    const int* __restrict__ tidx, const float* __restrict__ temb,
    const u16* __restrict__ TF, u16* __restrict__ RDIE,
    float* __restrict__ Wb, int s0, int CS)
{
    __shared__ u16 smem[32768];          // At 8192 | Bt 8192 | Tt(qp) 16384
    u16* At = smem;
    u16* Bt = smem + 8192;
    u16* Tt = smem + 16384;
    const int tid = threadIdx.x;
    const int row0 = blockIdx.x * 128;
    const int lane = tid & 63, wv = tid >> 6;
    const int wr = (wv >> 1) * 64, wc = (wv & 1) * 64;
    const int q = lane >> 4, c0 = lane & 15;

    floatx4 acc[4][4];
#pragma unroll
    for (int m = 0; m < 4; ++m)
#pragma unroll
        for (int n = 0; n < 4; ++n) acc[m][n] = (floatx4)0.f;

    // ---- GEMM3: x3 @ W1^T, K=128 ----
    for (int kt = 0; kt < 128; kt += 64) {
#pragma unroll
        for (int j = 0; j < 4; ++j) {
            int f = tid + j * 256; int r = f >> 3; int lg = (f & 7) ^ (r & 7);
            gl16(X3 + (size_t)(row0 + r) * 128 + kt + lg * 8, &At[f * 8]);
        }
#pragma unroll
        for (int j = 0; j < 4; ++j) {
            int f = tid + j * 256; int r = f >> 3; int lg = (f & 7) ^ (r & 7);
            gl16(W1h + (size_t)r * 128 + kt + lg * 8, &Bt[f * 8]);
        }
        __syncthreads();
#pragma unroll
        for (int kk = 0; kk < 2; ++kk) {
            half8 af[4], bf[4];
#pragma unroll
            for (int m = 0; m < 4; ++m) {
                int row = wr + m * 16 + c0;
                af[m] = *(half8*)&At[row * 64 + ((((kk << 2) | q)) ^ (row & 7)) * 8];
            }
#pragma unroll
            for (int n = 0; n < 4; ++n) {
                int row = wc + n * 16 + c0;
                bf[n] = *(half8*)&Bt[row * 64 + ((((kk << 2) | q)) ^ (row & 7)) * 8];
            }
#pragma unroll
            for (int m = 0; m < 4; ++m)
#pragma unroll
                for (int n = 0; n < 4; ++n)
                    acc[m][n] = __builtin_amdgcn_mfma_f32_16x16x32_f16(af[m], bf[n], acc[m][n], 0, 0, 0);
        }
        __syncthreads();
    }

    // ---- qp = acc + b1 -> Tt (swizzled); ie = qp + tf*te -> RDIE ----
    {
        float bv1[4];
#pragma unroll
        for (int n = 0; n < 4; ++n) bv1[n] = b1[wc + n * 16 + c0];
#pragma unroll
        for (int m = 0; m < 4; ++m)
#pragma unroll
            for (int r4 = 0; r4 < 4; ++r4) {
                int rloc = wr + m * 16 + q * 4 + r4;
                int grow = row0 + rloc;
                int nmap = gmap(grow, s0, CS);
                const float* terow = temb + (size_t)tidx[nmap] * 128;
#pragma unroll
                for (int n = 0; n < 4; ++n) {
                    int col = wc + n * 16 + c0;
                    float qp = acc[m][n][r4] + bv1[n];
                    int tile = col >> 6, cl = col & 63, gl = cl >> 3;
                    Tt[tile * 8192 + rloc * 64 + ((gl ^ (rloc & 7)) << 3) + (cl & 7)] = f2h(qp);
                    float tf = h2f(TF[(size_t)grow * 128 + col]);
                    RDIE[(size_t)grow * 384 + 256 + col] = f2h(fmaf(tf, terow[col], qp));
                }
            }
    }
    // stage Mkh (both k-tiles, 16KB) into Bt
#pragma unroll
    for (int j = 0; j < 4; ++j) {
        int f = tid + j * 256;
        int fl = f & 511;
        int ktile = f >> 9;
        int r = fl >> 3;
        int lg = (fl & 7) ^ (r & 7);
        gl16(Mkh + (size_t)r * 128 + ktile * 64 + lg * 8, &Bt[f * 8]);
    }
    __syncthreads();

    // ---- logits = qp @ Mkh^T ----
    const int wrW = wv * 32;
    floatx4 acc2[2][4];
#pragma unroll
    for (int m = 0; m < 2; ++m)
#pragma unroll
        for (int n = 0; n < 4; ++n) acc2[m][n] = (floatx4)0.f;
#pragma unroll
    for (int kt = 0; kt < 2; ++kt)
#pragma unroll
        for (int kk = 0; kk < 2; ++kk) {
            half8 af[2], bf[4];
#pragma unroll
            for (int m = 0; m < 2; ++m) {
                int row = wrW + m * 16 + c0;
                af[m] = *(half8*)&Tt[kt * 8192 + row * 64 + ((((kk << 2) | q)) ^ (row & 7)) * 8];
            }
#pragma unroll
            for (int n = 0; n < 4; ++n) {
                int row = n * 16 + c0;
                bf[n] = *(half8*)&Bt[kt * 4096 + row * 64 + ((((kk << 2) | q)) ^ (row & 7)) * 8];
            }
#pragma unroll
            for (int m = 0; m < 2; ++m)
#pragma unroll
                for (int n = 0; n < 4; ++n)
                    acc2[m][n] = __builtin_amdgcn_mfma_f32_16x16x32_f16(af[m], bf[n], acc2[m][n], 0, 0, 0);
        }
    __syncthreads();

    // ---- softmax ----
    float* Sred = (float*)smem;
#pragma unroll
    for (int m = 0; m < 2; ++m)
#pragma unroll
        for (int r4 = 0; r4 < 4; ++r4) {
            int row = wrW + m * 16 + q * 4 + r4;
#pragma unroll
            for (int n = 0; n < 4; ++n)
                Sred[row * 67 + n * 16 + c0] = acc2[m][n][r4];
        }
    __syncthreads();

    if (tid < 128) {
        float* s = &Sred[tid * 67];
        float mx = -3.0e38f;
#pragma unroll
        for (int m = 0; m < MM; ++m) mx = fmaxf(mx, s[m]);
        float sum = 0.f;
#pragma unroll
        for (int m = 0; m < MM; ++m) { float e = __expf(s[m] - mx); s[m] = e; sum += e; }
        float inv = 1.f / sum;
#pragma unroll
        for (int m = 0; m < MM; ++m) s[m] *= inv;
        s[50] = 0.f; s[51] = 0.f;
    }
    __syncthreads();

    for (int i = tid; i < 128 * 13; i += 256) {
        int row = i / 13, seg = i - row * 13;
        float4 v;
        v.x = Sred[row * 67 + seg * 4 + 0];
        v.y = Sred[row * 67 + seg * 4 + 1];
        v.z = Sred[row * 67 + seg * 4 + 2];
        v.w = Sred[row * 67 + seg * 4 + 3];
        *(float4*)(Wb + (size_t)(row0 + row) * WSTRIDE + seg * 4) = v;
    }
}

// ---------------------------------------------------------------------------
// fp16 MFMA GEMM (MODE 4 EAtab build, MODE 5 readout), BK=64,
// global_load_lds staging with XOR-granule swizzle. Grid dim3(4, rows/128):
// the 4 col-group blocks of a row-block dispatch adjacently (A re-reads hit
// L2/L3). MODE 5 writes per-col-group partials to Yf[row*4+by] (no atomics,
// no memset needed).
// ---------------------------------------------------------------------------
template <int MODE>
__global__ __launch_bounds__(256, 4) void gemm16(
    const u16* __restrict__ A, const u16* __restrict__ W0,
    const u16* __restrict__ W1, const float* __restrict__ b0,
    const float* __restrict__ b1, u16* __restrict__ Yh,
    float* __restrict__ Yf,
    u16* __restrict__ AUX, const float* __restrict__ predW,
    int K)
{
    __shared__ u16 smem[2 * 128 * 64];   // 32768 B
    u16* At = smem;
    u16* Bt = smem + 128 * 64;
    const int tid = threadIdx.x;
    const int row0 = blockIdx.y * 128;
    const int by = blockIdx.x;

    const u16* Wp;
    int col0;
    if constexpr (MODE == 4) { Wp = (by < 2) ? W0 : W1; col0 = (by & 1) * 128; }
    else { Wp = W0; col0 = by * 128; }
    const float* bias = (MODE == 4 && by >= 2) ? b1 : b0;

    floatx4 acc[4][4];
#pragma unroll
    for (int m = 0; m < 4; ++m)
#pragma unroll
        for (int n = 0; n < 4; ++n) acc[m][n] = (floatx4)0.f;

    const int lane = tid & 63, wv = tid >> 6;
    const int wr = (wv >> 1) * 64, wc = (wv & 1) * 64;
    const int q = lane >> 4, c0 = lane & 15;

    for (int kt = 0; kt < K; kt += 64) {
#pragma unroll
        for (int j = 0; j < 4; ++j) {
            int f = tid + j * 256;
            int r = f >> 3;
            int lg = (f & 7) ^ (r & 7);
            gl16(A + (size_t)(row0 + r) * K + kt + lg * 8, &At[f * 8]);
        }
#pragma unroll
        for (int j = 0; j < 4; ++j) {
            int f = tid + j * 256;
            int r = f >> 3;
            int lg = (f & 7) ^ (r & 7);
            gl16(Wp + (size_t)(col0 + r) * K + kt + lg * 8, &Bt[f * 8]);
        }
        __syncthreads();
#pragma unroll
        for (int kk = 0; kk < 2; ++kk) {
            half8 af[4], bf[4];
#pragma unroll
            for (int m = 0; m < 4; ++m) {
                int row = wr + m * 16 + c0;
                af[m] = *(half8*)&At[row * 64 + ((((kk << 2) | q)) ^ (row & 7)) * 8];
            }
#pragma unroll
            for (int n = 0; n < 4; ++n) {
                int row = wc + n * 16 + c0;
                bf[n] = *(half8*)&Bt[row * 64 + ((((kk << 2) | q)) ^ (row & 7)) * 8];
            }
#pragma unroll
            for (int m = 0; m < 4; ++m)
#pragma unroll
                for (int n = 0; n < 4; ++n)
                    acc[m][n] = __builtin_amdgcn_mfma_f32_16x16x32_f16(af[m], bf[n], acc[m][n], 0, 0, 0);
        }
        __syncthreads();
    }

    float bv[4];
#pragma unroll
    for (int n = 0; n < 4; ++n) bv[n] = bias[col0 + wc + n * 16 + c0];

    if constexpr (MODE == 5) {
        float pw[4];
#pragma unroll
        for (int n = 0; n < 4; ++n) pw[n] = predW[col0 + wc + n * 16 + c0];
        float* red = (float*)smem;          // [128][33] = 16896 B
#pragma unroll
        for (int m = 0; m < 4; ++m)
#pragma unroll
            for (int r4 = 0; r4 < 4; ++r4) {
                int row = wr + m * 16 + q * 4 + r4;
                float pp = 0.f;
#pragma unroll
                for (int n = 0; n < 4; ++n)
                    pp = fmaf(tanhfast(acc[m][n][r4] + bv[n]), pw[n], pp);
                red[row * 33 + (wv & 1) * 16 + c0] = pp;
            }
        __syncthreads();
        if (tid < 128) {
            float s = 0.f;
#pragma unroll
            for (int j = 0; j < 32; ++j) s += red[tid * 33 + j];
            Yf[(size_t)(row0 + tid) * 4 + by] = s;   // disjoint partials
        }
    } else { // MODE 4
#pragma unroll
        for (int m = 0; m < 4; ++m)
#pragma unroll
            for (int r4 = 0; r4 < 4; ++r4) {
                int row = row0 + wr + m * 16 + q * 4 + r4;
#pragma unroll
                for (int n = 0; n < 4; ++n) {
                    int col = col0 + wc + n * 16 + c0;
                    float v = acc[m][n][r4] + bv[n];
                    bool isE = (by < 2);
                    v = isE ? sigf(v) : tanhfast(v);
                    AUX[((size_t)row * 256 + col) * 2 + (isE ? 0 : 1)] = f2h(v);
                }
            }
    }
}

// ---------------------------------------------------------------------------
// DKVMN scan v9 (exact R8 revert — best measured 97.5us): 256 blocks (batch)
// x 256 threads (dim d). LDS double-buffered WT-step w tiles; register
// ping-pong source form (compiler folds it, measured best); packed-f2 math
// (mv += w*(a - e*mv)); e/a gathered from EAtab, prefetched a tile ahead.
// ---------------------------------------------------------------------------
__global__ __launch_bounds__(256, 1) void scan_kernel(
    const float* __restrict__ Wb, const int* __restrict__ qa_data,
    const u32* __restrict__ EAtab,
    const float* __restrict__ Mv0, float* __restrict__ MvSt,
    u16* __restrict__ RDIE, int CS, int s0, int first)
{
    __shared__ float wt[2][WT * WSTRIDE];   // 2 x 520 floats = 4160 B
    const int b = blockIdx.x;
    const int d = threadIdx.x;

    f2 mv[25];
    if (first) {
#pragma unroll
        for (int j = 0; j < 25; ++j) {
            mv[j].x = Mv0[(2 * j) * DV + d];
            mv[j].y = Mv0[(2 * j + 1) * DV + d];
        }
    } else {
#pragma unroll
        for (int j = 0; j < 25; ++j) {
            mv[j].x = MvSt[((size_t)b * MM + 2 * j) * DV + d];
            mv[j].y = MvSt[((size_t)b * MM + 2 * j + 1) * DV + d];
        }
    }

    const float* wbase = Wb + (size_t)b * CS * WSTRIDE;   // rows contiguous
    const int* qap = qa_data + (size_t)b * SQ + s0;
    u16* rp = RDIE + (size_t)b * CS * 384 + d;

    const int NT = CS / WT;
    const bool loader = (d < (WT * WSTRIDE / 4));   // 130 loader threads

    // Preload tile 0: W -> LDS buf0, ea -> regs (index then gather)
    if (loader) *(float4*)&wt[0][d * 4] = ld4(wbase + d * 4);
    u32 ea[WT];
    {
        int qi[WT];
#pragma unroll
        for (int i = 0; i < WT; ++i) qi[i] = qap[i];
#pragma unroll
        for (int i = 0; i < WT; ++i) ea[i] = EAtab[(size_t)qi[i] * DV + d];
    }
    __syncthreads();

    int cur = 0;
    for (int tile = 0; tile < NT; ++tile) {
        // Prefetch next tile (global -> regs); consumed after this tile
        float4 wreg;
        u32 ean[WT];
        const bool havenext = (tile + 1 < NT);
        if (havenext) {
            if (loader) wreg = ld4(wbase + (size_t)(tile + 1) * WT * WSTRIDE + d * 4);
            int qn[WT];
#pragma unroll
            for (int i = 0; i < WT; ++i) qn[i] = qap[(tile + 1) * WT + i];
#pragma unroll
            for (int i = 0; i < WT; ++i) ean[i] = EAtab[(size_t)qn[i] * DV + d];
        }

        // Register ping-pong over steps; preload step 0
        float4 wpp[2][13];
#pragma unroll
        for (int i = 0; i < 13; ++i)
            wpp[0][i] = *(const float4*)&wt[cur][i * 4];

#pragma unroll
        for (int s = 0; s < WT; ++s) {
            // issue step s+1's broadcast ds_reads into the other bank
            if (s + 1 < WT) {
#pragma unroll
                for (int i = 0; i < 13; ++i)
                    wpp[(s + 1) & 1][i] =
                        *(const float4*)&wt[cur][(s + 1) * WSTRIDE + i * 4];
            }
            const f2* w2 = (const f2*)wpp[s & 1];
            u32 eav = ea[s];
            float e = h2f((u16)(eav & 0xffff));
            float a = h2f((u16)(eav >> 16));
            f2 e2; e2.x = e; e2.y = e;
            f2 a2; a2.x = a; a2.y = a;
            f2 r0 = (f2)0.f, r1 = (f2)0.f, r2 = (f2)0.f, r3 = (f2)0.f;
#pragma unroll
            for (int j = 0; j < 24; j += 4) {
                f2 w_0 = w2[j + 0], w_1 = w2[j + 1], w_2 = w2[j + 2], w_3 = w2[j + 3];
                r0 += w_0 * mv[j + 0];
                r1 += w_1 * mv[j + 1];
                r2 += w_2 * mv[j + 2];
                r3 += w_3 * mv[j + 3];
                f2 t0 = a2 - e2 * mv[j + 0];
                f2 t1 = a2 - e2 * mv[j + 1];
                f2 t2 = a2 - e2 * mv[j + 2];
                f2 t3 = a2 - e2 * mv[j + 3];
                mv[j + 0] += w_0 * t0;
                mv[j + 1] += w_1 * t1;
                mv[j + 2] += w_2 * t2;
                mv[j + 3] += w_3 * t3;
            }
            {
                f2 w24 = w2[24];
                r0 += w24 * mv[24];
                f2 t = a2 - e2 * mv[24];
                mv[24] += w24 * t;
            }
            f2 rs = (r0 + r1) + (r2 + r3);
            rp[(size_t)(tile * WT + s) * 384] = f2h(rs.x + rs.y);
        }

        if (havenext) {
            if (loader) *(float4*)&wt[1 - cur][d * 4] = wreg;
#pragma unroll
            for (int i = 0; i < WT; ++i) ea[i] = ean[i];
            __syncthreads();
            cur ^= 1;
        }
    }

#pragma unroll
    for (int j = 0; j < 25; ++j) {
        MvSt[((size_t)b * MM + 2 * j) * DV + d]     = mv[j].x;
        MvSt[((size_t)b * MM + 2 * j + 1) * DV + d] = mv[j].y;
    }
}

// ---------------------------------------------------------------------------
// loss + outputs (pred partials read as float4 from bufP4; no atomics)
// ---------------------------------------------------------------------------
__global__ __launch_bounds__(256) void loss_part(
    const float* __restrict__ P4, const int* __restrict__ target,
    const float* __restrict__ pred_b, float* __restrict__ out,
    float* __restrict__ R2, int s0, int CS, int Nc)
{
    int l = blockIdx.x * 256 + threadIdx.x;
    float le = 0.f, mf = 0.f;
    if (l < Nc) {
        int n = gmap(l, s0, CS);
        float4 p4 = ld4(P4 + (size_t)l * 4);
        float p = (p4.x + p4.y) + (p4.z + p4.w) + pred_b[0];
        int t = target[n];
        float y = (t >= 1) ? (float)(t - 1) : 0.f;
        float sig = 1.f / (1.f + __expf(-p));
        if (t >= 1) {
            mf = 1.f;
            le = fmaxf(p, 0.f) + log1pf(__expf(-fabsf(p))) - p * y;
        }
        out[1 + n] = sig * mf;
        out[1 + NROWS + n] = y * mf;
    }
#pragma unroll
    for (int off = 32; off; off >>= 1) {
        le += __shfl_down(le, off);
        mf += __shfl_down(mf, off);
    }
    __shared__ float sl[4], sm[4];
    int wid = threadIdx.x >> 6;
    if ((threadIdx.x & 63) == 0) { sl[wid] = le; sm[wid] = mf; }
    __syncthreads();
    if (threadIdx.x == 0) {
        atomicAdd(R2, sl[0] + sl[1] + sl[2] + sl[3]);
        atomicAdd(R2 + 1, sm[0] + sm[1] + sm[2] + sm[3]);
    }
}

__global__ void loss_fin(const float* __restrict__ R2, float* __restrict__ out)
{
    out[0] = R2[0] / fmaxf(R2[1], 1.f);
}

// ---------------------------------------------------------------------------
extern "C" void kernel_launch(void* const* d_in, const int* in_sizes, int n_in,
                              void* d_out, int out_size, void* d_ws, size_t ws_size,
                              hipStream_t stream)
{
    const int* q_data       = (const int*)d_in[0];
    const int* qa_data      = (const int*)d_in[1];
    const int* target       = (const int*)d_in[2];
    const int* time_data    = (const int*)d_in[3];
    const int* attempt_data = (const int*)d_in[4];
    const int* hint_data    = (const int*)d_in[5];
    const int* hintT_data   = (const int*)d_in[6];
    const float* q_emb    = (const float*)d_in[7];
    const float* qa_emb   = (const float*)d_in[8];
    const float* time_emb = (const float*)d_in[9];
    const float* att_emb  = (const float*)d_in[10];
    const float* ht_emb   = (const float*)d_in[11];
    const float* Mk       = (const float*)d_in[12];
    const float* Mv0      = (const float*)d_in[13];
    const float* diff_W   = (const float*)d_in[14];
    const float* diff_b   = (const float*)d_in[15];
    const float* diff2_W  = (const float*)d_in[16];
    const float* diff2_b  = (const float*)d_in[17];
    const float* erase_W  = (const float*)d_in[18];
    const float* erase_b  = (const float*)d_in[19];
    const float* add_W    = (const float*)d_in[20];
    const float* add_b    = (const float*)d_in[21];
    const float* read_W   = (const float*)d_in[22];
    const float* read_b   = (const float*)d_in[23];
    const float* pred_W   = (const float*)d_in[24];
    const float* pred_b   = (const float*)d_in[25];
    float* out = (float*)d_out;
    (void)in_sizes; (void)n_in; (void)out_size;

    // Adaptive chunking over S (CS must be divisible by WT=10).
    // Per-row bytes: wbuf 208 + bufP4 16 + Xp 512 + RDIE 768 = 1504
    // (QEp/S3p now alias RDIE[:,0:256) — written by prep, read by gemm12,
    //  overwritten later by the scan's rd)
    static const int cs_opts[] = {500, 250, 100, 50, 20, 10};
    const size_t FIXED = 44800000ull;
    int CS = 0;
    for (int i = 0; i < 6; ++i) {
        size_t need = (size_t)NB * cs_opts[i] * 1504ull + FIXED;
        if (need <= ws_size) { CS = cs_opts[i]; break; }
    }
    if (CS == 0) return;
    const int NCH = SQ / CS;
    const int Nc = NB * CS;

    // Workspace layout (16B-aligned sections)
    float* MvSt  = (float*)d_ws;                         // [NB*MM*DV]
    float* wbuf  = MvSt + (size_t)NB * MM * DV;          // [Nc*52]
    float* bufP4 = wbuf + (size_t)Nc * WSTRIDE;          // [Nc*4]
    float* bufR2 = bufP4 + (size_t)Nc * 4;               // [4]
    u16*  Xp     = (u16*)(bufR2 + 4);                    // [2Nc*128]
    u16*  RDIE   = Xp + (size_t)2 * Nc * 128;            // [Nc*384]
    u16*  dWh    = RDIE + (size_t)Nc * 384;              // 16384
    u16*  d2Wh   = dWh + 16384;                          // 16384
    u16*  eWh    = d2Wh + 16384;                         // 65536
    u16*  aWh    = eWh + 65536;                          // 65536
    u16*  rWh    = aWh + 65536;                          // 196608
    u16*  qaEh   = rWh + 196608;                         // 5,120,256
    u16*  Mkh    = qaEh + 5120256;                       // 8,192 (64x128)
    u32*  EAtab  = (u32*)(Mkh + 8192);                   // [NQA*256] u32 = 20.6 MB

    // Fused one-time weight conversions (5 matrices -> contiguous dWh..rWh)
    wcvt<<<352, 256, 0, stream>>>(diff_W, diff2_W, erase_W, add_W, read_W, dWh);
    cvt16<<<5001, 256, 0, stream>>>(qa_emb, qaEh, 5120256 / 4);
    mkcvt<<<8, 256, 0, stream>>>(Mk, Mkh);
    hipMemsetAsync(bufR2, 0, 4 * sizeof(float), stream);

    // One-time e/a gate TABLE over all distinct qa indices (NQA rows)
    gemm16<4><<<dim3(4, NQA / 128), 256, 0, stream>>>(
        qaEh, eWh, aWh, erase_b, add_b, nullptr, nullptr,
        (u16*)EAtab, nullptr, 256);

    for (int c = 0; c < NCH; ++c) {
        const int s0 = c * CS;

        prep128<<<Nc / 8, 256, 0, stream>>>(
            q_data, time_data, attempt_data, hint_data, hintT_data,
            q_emb, time_emb, att_emb, ht_emb, Xp, RDIE, s0, CS, Nc);

        // FUSED G1+G2: tf (rows<Nc) and x3 (rows>=Nc) in one pass
        gemm12<<<2 * Nc / 128, 256, 0, stream>>>(
            Xp, dWh, d2Wh, diff_b, diff2_b, Xp, RDIE, Nc);

        // FUSED G3+wsoftmax: qp in LDS; ie -> RDIE[:,256:384); w -> wbuf
        gemm3w<<<Nc / 128, 256, 0, stream>>>(
            Xp + (size_t)Nc * 128, dWh, diff_b, Mkh,
            time_data, time_emb, Xp, RDIE, wbuf, s0, CS);

        // scan -> RD fp16 into RDIE[:,0:256); e/a gathered from EAtab
        scan_kernel<<<NB, DV, 0, stream>>>(
            wbuf, qa_data, EAtab, Mv0, MvSt, RDIE, CS, s0, c == 0 ? 1 : 0);

        // G5: rc = tanh([rd|ie] @ read_W^T + b); pred partials -> bufP4
        gemm16<5><<<dim3(4, Nc / 128), 256, 0, stream>>>(
            RDIE, rWh, nullptr, read_b, nullptr, nullptr, bufP4,
            nullptr, pred_W, 384);

        loss_part<<<Nc / 256, 256, 0, stream>>>(bufP4, target, pred_b, out, bufR2, s0, CS, Nc);
    }

    loss_fin<<<1, 1, 0, stream>>>(bufR2, out);
}

// Round 13
// 601.284 us; speedup vs baseline: 1.1024x; 1.0154x over previous
//
#include <hip/hip_runtime.h>
#include <cstdint>
#include <cstddef>

// Problem constants
#define NB 256
#define SQ 500
#define NROWS (NB * SQ)   // 128000
#define DQ 128
#define DV 256
#define MM 50
#define FF 512
#define NQA 20096         // padded distinct qa indices (2*NQ+1 = 20001 -> 157*128)
#define WSTRIDE 52        // padded w-row stride (16B aligned)
#define WT 10             // scan LDS tile: steps per stage

typedef _Float16 half8 __attribute__((ext_vector_type(8)));
typedef float floatx4 __attribute__((ext_vector_type(4)));
typedef float f2 __attribute__((ext_vector_type(2)));
typedef unsigned int u32;
typedef unsigned short u16;

typedef __attribute__((address_space(1))) void gvoid;
typedef __attribute__((address_space(3))) void lvoid;

// async global->LDS, 16B per lane; LDS dest is wave-uniform base + lane*16
__device__ __forceinline__ void gl16(const u16* g, u16* l) {
    __builtin_amdgcn_global_load_lds((gvoid*)g, (lvoid*)l, 16, 0, 0);
}

__device__ __forceinline__ float4 ld4(const float* p) {
    return *reinterpret_cast<const float4*>(p);
}
__device__ __forceinline__ float sigf(float x) { return 1.f / (1.f + __expf(-x)); }
__device__ __forceinline__ float tanhfast(float x) { return 2.f / (1.f + __expf(-2.f * x)) - 1.f; }
__device__ __forceinline__ int gmap(int l, int s0, int CS) {
    int b = (unsigned)l / (unsigned)CS;
    return b * SQ + s0 + (l - b * CS);
}
__device__ __forceinline__ void st4h(u16* dst, float4 v) {
    _Float16 h0 = (_Float16)v.x, h1 = (_Float16)v.y, h2 = (_Float16)v.z, h3 = (_Float16)v.w;
    ushort4 u;
    u.x = *(u16*)&h0; u.y = *(u16*)&h1; u.z = *(u16*)&h2; u.w = *(u16*)&h3;
    *(ushort4*)dst = u;
}
__device__ __forceinline__ float h2f(u16 b) { _Float16 h; *(u16*)&h = b; return (float)h; }
__device__ __forceinline__ u16 f2h(float x) { _Float16 h = (_Float16)x; return *(u16*)&h; }

// component k (constant) of a float4 array, static-index safe under unroll
#define CBF(arr, k) ((((k) & 3) == 0) ? arr[(k) >> 2].x : \
                     (((k) & 3) == 1) ? arr[(k) >> 2].y : \
                     (((k) & 3) == 2) ? arr[(k) >> 2].z : arr[(k) >> 2].w)

// ---------------------------------------------------------------------------
// fp32 -> fp16 conversion (vec4)
// ---------------------------------------------------------------------------
__global__ __launch_bounds__(256) void cvt16(
    const float* __restrict__ s, u16* __restrict__ d, int n4)
{
    int i = blockIdx.x * 256 + threadIdx.x;
    if (i < n4) st4h(d + 4 * (size_t)i, ld4(s + 4 * (size_t)i));
}

// ---------------------------------------------------------------------------
// fused fp16 conversion of the 5 weight matrices (contiguous dst layout)
// ---------------------------------------------------------------------------
__global__ __launch_bounds__(256) void wcvt(
    const float* __restrict__ s0, const float* __restrict__ s1,
    const float* __restrict__ s2, const float* __restrict__ s3,
    const float* __restrict__ s4, u16* __restrict__ dst)
{
    int i = blockIdx.x * 256 + threadIdx.x;
    if (i >= 90112) return;
    const float* s; int off;
    if (i < 4096)       { s = s0; off = 0; }
    else if (i < 8192)  { s = s1; off = 4096; }
    else if (i < 24576) { s = s2; off = 8192; }
    else if (i < 40960) { s = s3; off = 24576; }
    else                { s = s4; off = 40960; }
    st4h(dst + 4 * (size_t)i, ld4(s + 4 * (size_t)(i - off)));
}

// ---------------------------------------------------------------------------
// Mk [50,128] fp32 -> Mkh [64,128] fp16, rows 50..63 zeroed
// ---------------------------------------------------------------------------
__global__ __launch_bounds__(256) void mkcvt(
    const float* __restrict__ Mk, u16* __restrict__ Mkh)
{
    int i = blockIdx.x * 256 + threadIdx.x;   // 2048 float4 slots
    if (i >= 64 * 32) return;
    int row = i >> 5;
    float4 v = (row < MM) ? ld4(Mk + (size_t)row * DQ + (i & 31) * 4)
                          : float4{0.f, 0.f, 0.f, 0.f};
    st4h(Mkh + 4 * (size_t)i, v);
}

// ---------------------------------------------------------------------------
// prep: Xp rows [0,Nc) = fp16(te+qe); rows [Nc,2Nc) = fp16(he+hte+ae+qe);
// qe -> RDIE[l*384 + 0:128), s3 -> RDIE[l*384 + 128:256)   (aliased region:
// consumed by gemm12's epilogue, later overwritten by the scan's rd)
// ---------------------------------------------------------------------------
__global__ __launch_bounds__(256) void prep128(
    const int* __restrict__ q_data, const int* __restrict__ time_data,
    const int* __restrict__ attempt_data, const int* __restrict__ hint_data,
    const int* __restrict__ hintT_data,
    const float* __restrict__ q_emb, const float* __restrict__ time_emb,
    const float* __restrict__ attempt_emb, const float* __restrict__ ht_emb,
    u16* __restrict__ Xp, u16* __restrict__ RDIE,
    int s0, int CS, int Nc)
{
    int g = blockIdx.x * 256 + threadIdx.x;
    int l = g >> 5;
    int kq = (g & 31) << 2;
    if (l >= Nc) return;
    int n = gmap(l, s0, CS);
    float4 qe  = ld4(q_emb       + (size_t)q_data[n]       * DQ + kq);
    float4 te  = ld4(time_emb    + (size_t)time_data[n]    * DQ + kq);
    float4 ae  = ld4(attempt_emb + (size_t)attempt_data[n] * DQ + kq);
    float4 he  = ld4(ht_emb      + (size_t)hint_data[n]    * DQ + kq);
    float4 hte = ld4(ht_emb      + (size_t)hintT_data[n]   * DQ + kq);
    size_t off = (size_t)l * DQ + kq;
    float4 x1, s3, x2;
    x1.x = te.x + qe.x; x1.y = te.y + qe.y; x1.z = te.z + qe.z; x1.w = te.w + qe.w;
    s3.x = he.x + hte.x + ae.x; s3.y = he.y + hte.y + ae.y;
    s3.z = he.z + hte.z + ae.z; s3.w = he.w + hte.w + ae.w;
    x2.x = s3.x + qe.x; x2.y = s3.y + qe.y; x2.z = s3.z + qe.z; x2.w = s3.w + qe.w;
    st4h(Xp + off, x1);
    st4h(Xp + (size_t)Nc * DQ + off, x2);
    st4h(RDIE + (size_t)l * 384 + kq, qe);
    st4h(RDIE + (size_t)l * 384 + 128 + kq, s3);
}

// ---------------------------------------------------------------------------
// FUSED G1+G2 (R8-verified): Y2 = sig(tanh(X @ W1^T + b1) @ W2^T + b2),
// MODE-2 epilogue (qe/s3 read from the aliased RDIE region, stride 384).
// ---------------------------------------------------------------------------
__global__ __launch_bounds__(256, 2) void gemm12(
    const u16* __restrict__ A, const u16* __restrict__ W1h,
    const u16* __restrict__ W2h, const float* __restrict__ b1,
    const float* __restrict__ b2, u16* __restrict__ Yh,
    const u16* __restrict__ RDIE, int Nc)
{
    __shared__ u16 smem[32768];          // 64KB: At 8192 | Bt 8192 | Tt 16384
    u16* At = smem;
    u16* Bt = smem + 8192;
    u16* Tt = smem + 16384;
    const int tid = threadIdx.x;
    const int row0 = blockIdx.x * 128;
    const int lane = tid & 63, wv = tid >> 6;
    const int wr = (wv >> 1) * 64, wc = (wv & 1) * 64;
    const int q = lane >> 4, c0 = lane & 15;

    floatx4 acc[4][4];
#pragma unroll
    for (int m = 0; m < 4; ++m)
#pragma unroll
        for (int n = 0; n < 4; ++n) acc[m][n] = (floatx4)0.f;

    // ---- GEMM1: X @ W1^T, K=128 ----
    for (int kt = 0; kt < 128; kt += 64) {
#pragma unroll
        for (int j = 0; j < 4; ++j) {
            int f = tid + j * 256; int r = f >> 3; int lg = (f & 7) ^ (r & 7);
            gl16(A + (size_t)(row0 + r) * 128 + kt + lg * 8, &At[f * 8]);
        }
#pragma unroll
        for (int j = 0; j < 4; ++j) {
            int f = tid + j * 256; int r = f >> 3; int lg = (f & 7) ^ (r & 7);
            gl16(W1h + (size_t)r * 128 + kt + lg * 8, &Bt[f * 8]);
        }
        __syncthreads();
#pragma unroll
        for (int kk = 0; kk < 2; ++kk) {
            half8 af[4], bf[4];
#pragma unroll
            for (int m = 0; m < 4; ++m) {
                int row = wr + m * 16 + c0;
                af[m] = *(half8*)&At[row * 64 + ((((kk << 2) | q)) ^ (row & 7)) * 8];
            }
#pragma unroll
            for (int n = 0; n < 4; ++n) {
                int row = wc + n * 16 + c0;
                bf[n] = *(half8*)&Bt[row * 64 + ((((kk << 2) | q)) ^ (row & 7)) * 8];
            }
#pragma unroll
            for (int m = 0; m < 4; ++m)
#pragma unroll
                for (int n = 0; n < 4; ++n)
                    acc[m][n] = __builtin_amdgcn_mfma_f32_16x16x32_f16(af[m], bf[n], acc[m][n], 0, 0, 0);
        }
        __syncthreads();
    }

    // ---- T = tanh(acc + b1) -> Tt (two swizzled [128][64] tiles) ----
    {
        float bv1[4];
#pragma unroll
        for (int n = 0; n < 4; ++n) bv1[n] = b1[wc + n * 16 + c0];
#pragma unroll
        for (int m = 0; m < 4; ++m)
#pragma unroll
            for (int r4 = 0; r4 < 4; ++r4) {
                int row = wr + m * 16 + q * 4 + r4;
#pragma unroll
                for (int n = 0; n < 4; ++n) {
                    int col = wc + n * 16 + c0;
                    float v = tanhfast(acc[m][n][r4] + bv1[n]);
                    int tile = col >> 6, cl = col & 63, gl = cl >> 3;
                    Tt[tile * 8192 + row * 64 + ((gl ^ (row & 7)) << 3) + (cl & 7)] = f2h(v);
                }
            }
    }
#pragma unroll
    for (int m = 0; m < 4; ++m)
#pragma unroll
        for (int n = 0; n < 4; ++n) acc[m][n] = (floatx4)0.f;

    // stage W2 kt=0 alongside T writes
#pragma unroll
    for (int j = 0; j < 4; ++j) {
        int f = tid + j * 256; int r = f >> 3; int lg = (f & 7) ^ (r & 7);
        gl16(W2h + (size_t)r * 128 + 0 + lg * 8, &Bt[f * 8]);
    }
    __syncthreads();

    // ---- GEMM2: T @ W2^T, K=128 (T resident in Tt) ----
#pragma unroll
    for (int kt = 0; kt < 2; ++kt) {
#pragma unroll
        for (int kk = 0; kk < 2; ++kk) {
            half8 af[4], bf[4];
#pragma unroll
            for (int m = 0; m < 4; ++m) {
                int row = wr + m * 16 + c0;
                af[m] = *(half8*)&Tt[kt * 8192 + row * 64 + ((((kk << 2) | q)) ^ (row & 7)) * 8];
            }
#pragma unroll
            for (int n = 0; n < 4; ++n) {
                int row = wc + n * 16 + c0;
                bf[n] = *(half8*)&Bt[row * 64 + ((((kk << 2) | q)) ^ (row & 7)) * 8];
            }
#pragma unroll
            for (int m = 0; m < 4; ++m)
#pragma unroll
                for (int n = 0; n < 4; ++n)
                    acc[m][n] = __builtin_amdgcn_mfma_f32_16x16x32_f16(af[m], bf[n], acc[m][n], 0, 0, 0);
        }
        if (kt == 0) {
            __syncthreads();
#pragma unroll
            for (int j = 0; j < 4; ++j) {
                int f = tid + j * 256; int r = f >> 3; int lg = (f & 7) ^ (r & 7);
                gl16(W2h + (size_t)r * 128 + 64 + lg * 8, &Bt[f * 8]);
            }
            __syncthreads();
        }
    }

    // ---- MODE-2 epilogue (qe/s3 from aliased RDIE, stride 384) ----
    float bv[4];
#pragma unroll
    for (int n = 0; n < 4; ++n) bv[n] = b2[wc + n * 16 + c0];
#pragma unroll
    for (int m = 0; m < 4; ++m)
#pragma unroll
        for (int r4 = 0; r4 < 4; ++r4) {
            int row = row0 + wr + m * 16 + q * 4 + r4;
#pragma unroll
            for (int n = 0; n < 4; ++n) {
                int col = wc + n * 16 + c0;
                float v = sigf(acc[m][n][r4] + bv[n]);
                if (row < Nc) {
                    Yh[(size_t)row * 128 + col] = f2h(v);
                } else {
                    size_t o = (size_t)(row - Nc) * 384 + col;
                    float qe = h2f(RDIE[o]), s3 = h2f(RDIE[o + 128]);
                    Yh[(size_t)row * 128 + col] = f2h(fmaf(v, s3, qe));
                }
            }
        }
}

// ---------------------------------------------------------------------------
// FUSED G3+wsoftmax (R8-verified): qp in LDS; ie -> RDIE; softmax -> Wb.
// ---------------------------------------------------------------------------
__global__ __launch_bounds__(256, 2) void gemm3w(
    const u16* __restrict__ X3, const u16* __restrict__ W1h,
    const float* __restrict__ b1, const u16* __restrict__ Mkh,
    const int* __restrict__ tidx, const float* __restrict__ temb,
    const u16* __restrict__ TF, u16* __restrict__ RDIE,
    float* __restrict__ Wb, int s0, int CS)
{
    __shared__ u16 smem[32768];          // At 8192 | Bt 8192 | Tt(qp) 16384
    u16* At = smem;
    u16* Bt = smem + 8192;
    u16* Tt = smem + 16384;
    const int tid = threadIdx.x;
    const int row0 = blockIdx.x * 128;
    const int lane = tid & 63, wv = tid >> 6;
    const int wr = (wv >> 1) * 64, wc = (wv & 1) * 64;
    const int q = lane >> 4, c0 = lane & 15;

    floatx4 acc[4][4];
#pragma unroll
    for (int m = 0; m < 4; ++m)
#pragma unroll
        for (int n = 0; n < 4; ++n) acc[m][n] = (floatx4)0.f;

    // ---- GEMM3: x3 @ W1^T, K=128 ----
    for (int kt = 0; kt < 128; kt += 64) {
#pragma unroll
        for (int j = 0; j < 4; ++j) {
            int f = tid + j * 256; int r = f >> 3; int lg = (f & 7) ^ (r & 7);
            gl16(X3 + (size_t)(row0 + r) * 128 + kt + lg * 8, &At[f * 8]);
        }
#pragma unroll
        for (int j = 0; j < 4; ++j) {
            int f = tid + j * 256; int r = f >> 3; int lg = (f & 7) ^ (r & 7);
            gl16(W1h + (size_t)r * 128 + kt + lg * 8, &Bt[f * 8]);
        }
        __syncthreads();
#pragma unroll
        for (int kk = 0; kk < 2; ++kk) {
            half8 af[4], bf[4];
#pragma unroll
            for (int m = 0; m < 4; ++m) {
                int row = wr + m * 16 + c0;
                af[m] = *(half8*)&At[row * 64 + ((((kk << 2) | q)) ^ (row & 7)) * 8];
            }
#pragma unroll
            for (int n = 0; n < 4; ++n) {
                int row = wc + n * 16 + c0;
                bf[n] = *(half8*)&Bt[row * 64 + ((((kk << 2) | q)) ^ (row & 7)) * 8];
            }
#pragma unroll
            for (int m = 0; m < 4; ++m)
#pragma unroll
                for (int n = 0; n < 4; ++n)
                    acc[m][n] = __builtin_amdgcn_mfma_f32_16x16x32_f16(af[m], bf[n], acc[m][n], 0, 0, 0);
        }
        __syncthreads();
    }

    // ---- qp = acc + b1 -> Tt (swizzled); ie = qp + tf*te -> RDIE ----
    {
        float bv1[4];
#pragma unroll
        for (int n = 0; n < 4; ++n) bv1[n] = b1[wc + n * 16 + c0];
#pragma unroll
        for (int m = 0; m < 4; ++m)
#pragma unroll
            for (int r4 = 0; r4 < 4; ++r4) {
                int rloc = wr + m * 16 + q * 4 + r4;
                int grow = row0 + rloc;
                int nmap = gmap(grow, s0, CS);
                const float* terow = temb + (size_t)tidx[nmap] * 128;
#pragma unroll
                for (int n = 0; n < 4; ++n) {
                    int col = wc + n * 16 + c0;
                    float qp = acc[m][n][r4] + bv1[n];
                    int tile = col >> 6, cl = col & 63, gl = cl >> 3;
                    Tt[tile * 8192 + rloc * 64 + ((gl ^ (rloc & 7)) << 3) + (cl & 7)] = f2h(qp);
                    float tf = h2f(TF[(size_t)grow * 128 + col]);
                    RDIE[(size_t)grow * 384 + 256 + col] = f2h(fmaf(tf, terow[col], qp));
                }
            }
    }
    // stage Mkh (both k-tiles, 16KB) into Bt
#pragma unroll
    for (int j = 0; j < 4; ++j) {
        int f = tid + j * 256;
        int fl = f & 511;
        int ktile = f >> 9;
        int r = fl >> 3;
        int lg = (fl & 7) ^ (r & 7);
        gl16(Mkh + (size_t)r * 128 + ktile * 64 + lg * 8, &Bt[f * 8]);
    }
    __syncthreads();

    // ---- logits = qp @ Mkh^T ----
    const int wrW = wv * 32;
    floatx4 acc2[2][4];
#pragma unroll
    for (int m = 0; m < 2; ++m)
#pragma unroll
        for (int n = 0; n < 4; ++n) acc2[m][n] = (floatx4)0.f;
#pragma unroll
    for (int kt = 0; kt < 2; ++kt)
#pragma unroll
        for (int kk = 0; kk < 2; ++kk) {
            half8 af[2], bf[4];
#pragma unroll
            for (int m = 0; m < 2; ++m) {
                int row = wrW + m * 16 + c0;
                af[m] = *(half8*)&Tt[kt * 8192 + row * 64 + ((((kk << 2) | q)) ^ (row & 7)) * 8];
            }
#pragma unroll
            for (int n = 0; n < 4; ++n) {
                int row = n * 16 + c0;
                bf[n] = *(half8*)&Bt[kt * 4096 + row * 64 + ((((kk << 2) | q)) ^ (row & 7)) * 8];
            }
#pragma unroll
            for (int m = 0; m < 2; ++m)
#pragma unroll
                for (int n = 0; n < 4; ++n)
                    acc2[m][n] = __builtin_amdgcn_mfma_f32_16x16x32_f16(af[m], bf[n], acc2[m][n], 0, 0, 0);
        }
    __syncthreads();

    // ---- softmax ----
    float* Sred = (float*)smem;
#pragma unroll
    for (int m = 0; m < 2; ++m)
#pragma unroll
        for (int r4 = 0; r4 < 4; ++r4) {
            int row = wrW + m * 16 + q * 4 + r4;
#pragma unroll
            for (int n = 0; n < 4; ++n)
                Sred[row * 67 + n * 16 + c0] = acc2[m][n][r4];
        }
    __syncthreads();

    if (tid < 128) {
        float* s = &Sred[tid * 67];
        float mx = -3.0e38f;
#pragma unroll
        for (int m = 0; m < MM; ++m) mx = fmaxf(mx, s[m]);
        float sum = 0.f;
#pragma unroll
        for (int m = 0; m < MM; ++m) { float e = __expf(s[m] - mx); s[m] = e; sum += e; }
        float inv = 1.f / sum;
#pragma unroll
        for (int m = 0; m < MM; ++m) s[m] *= inv;
        s[50] = 0.f; s[51] = 0.f;
    }
    __syncthreads();

    for (int i = tid; i < 128 * 13; i += 256) {
        int row = i / 13, seg = i - row * 13;
        float4 v;
        v.x = Sred[row * 67 + seg * 4 + 0];
        v.y = Sred[row * 67 + seg * 4 + 1];
        v.z = Sred[row * 67 + seg * 4 + 2];
        v.w = Sred[row * 67 + seg * 4 + 3];
        *(float4*)(Wb + (size_t)(row0 + row) * WSTRIDE + seg * 4) = v;
    }
}

// ---------------------------------------------------------------------------
// fp16 MFMA GEMM (MODE 4 EAtab build, MODE 5 readout), BK=64,
// global_load_lds staging with XOR-granule swizzle. Grid dim3(4, rows/128).
// MODE 5 writes per-col-group partials to Yf[row*4+by] (no atomics).
// ---------------------------------------------------------------------------
template <int MODE>
__global__ __launch_bounds__(256, 4) void gemm16(
    const u16* __restrict__ A, const u16* __restrict__ W0,
    const u16* __restrict__ W1, const float* __restrict__ b0,
    const float* __restrict__ b1, u16* __restrict__ Yh,
    float* __restrict__ Yf,
    u16* __restrict__ AUX, const float* __restrict__ predW,
    int K)
{
    __shared__ u16 smem[2 * 128 * 64];   // 32768 B
    u16* At = smem;
    u16* Bt = smem + 128 * 64;
    const int tid = threadIdx.x;
    const int row0 = blockIdx.y * 128;
    const int by = blockIdx.x;

    const u16* Wp;
    int col0;
    if constexpr (MODE == 4) { Wp = (by < 2) ? W0 : W1; col0 = (by & 1) * 128; }
    else { Wp = W0; col0 = by * 128; }
    const float* bias = (MODE == 4 && by >= 2) ? b1 : b0;

    floatx4 acc[4][4];
#pragma unroll
    for (int m = 0; m < 4; ++m)
#pragma unroll
        for (int n = 0; n < 4; ++n) acc[m][n] = (floatx4)0.f;

    const int lane = tid & 63, wv = tid >> 6;
    const int wr = (wv >> 1) * 64, wc = (wv & 1) * 64;
    const int q = lane >> 4, c0 = lane & 15;

    for (int kt = 0; kt < K; kt += 64) {
#pragma unroll
        for (int j = 0; j < 4; ++j) {
            int f = tid + j * 256;
            int r = f >> 3;
            int lg = (f & 7) ^ (r & 7);
            gl16(A + (size_t)(row0 + r) * K + kt + lg * 8, &At[f * 8]);
        }
#pragma unroll
        for (int j = 0; j < 4; ++j) {
            int f = tid + j * 256;
            int r = f >> 3;
            int lg = (f & 7) ^ (r & 7);
            gl16(Wp + (size_t)(col0 + r) * K + kt + lg * 8, &Bt[f * 8]);
        }
        __syncthreads();
#pragma unroll
        for (int kk = 0; kk < 2; ++kk) {
            half8 af[4], bf[4];
#pragma unroll
            for (int m = 0; m < 4; ++m) {
                int row = wr + m * 16 + c0;
                af[m] = *(half8*)&At[row * 64 + ((((kk << 2) | q)) ^ (row & 7)) * 8];
            }
#pragma unroll
            for (int n = 0; n < 4; ++n) {
                int row = wc + n * 16 + c0;
                bf[n] = *(half8*)&Bt[row * 64 + ((((kk << 2) | q)) ^ (row & 7)) * 8];
            }
#pragma unroll
            for (int m = 0; m < 4; ++m)
#pragma unroll
                for (int n = 0; n < 4; ++n)
                    acc[m][n] = __builtin_amdgcn_mfma_f32_16x16x32_f16(af[m], bf[n], acc[m][n], 0, 0, 0);
        }
        __syncthreads();
    }

    float bv[4];
#pragma unroll
    for (int n = 0; n < 4; ++n) bv[n] = bias[col0 + wc + n * 16 + c0];

    if constexpr (MODE == 5) {
        float pw[4];
#pragma unroll
        for (int n = 0; n < 4; ++n) pw[n] = predW[col0 + wc + n * 16 + c0];
        float* red = (float*)smem;          // [128][33] = 16896 B
#pragma unroll
        for (int m = 0; m < 4; ++m)
#pragma unroll
            for (int r4 = 0; r4 < 4; ++r4) {
                int row = wr + m * 16 + q * 4 + r4;
                float pp = 0.f;
#pragma unroll
                for (int n = 0; n < 4; ++n)
                    pp = fmaf(tanhfast(acc[m][n][r4] + bv[n]), pw[n], pp);
                red[row * 33 + (wv & 1) * 16 + c0] = pp;
            }
        __syncthreads();
        if (tid < 128) {
            float s = 0.f;
#pragma unroll
            for (int j = 0; j < 32; ++j) s += red[tid * 33 + j];
            Yf[(size_t)(row0 + tid) * 4 + by] = s;   // disjoint partials
        }
    } else { // MODE 4
#pragma unroll
        for (int m = 0; m < 4; ++m)
#pragma unroll
            for (int r4 = 0; r4 < 4; ++r4) {
                int row = row0 + wr + m * 16 + q * 4 + r4;
#pragma unroll
                for (int n = 0; n < 4; ++n) {
                    int col = col0 + wc + n * 16 + c0;
                    float v = acc[m][n][r4] + bv[n];
                    bool isE = (by < 2);
                    v = isE ? sigf(v) : tanhfast(v);
                    AUX[((size_t)row * 256 + col) * 2 + (isE ? 0 : 1)] = f2h(v);
                }
            }
    }
}

// ---------------------------------------------------------------------------
// DKVMN scan v11: v9 structure + sched_barrier(0)-pinned register double
// buffer. v9/v10's source-level ping-pong was sunk by the machine scheduler
// (loads placed at uses -> full LDS latency exposed; VGPR stayed 104).
// sched_barrier(0) is a hard scheduling fence the sinking cannot cross:
//   load bankB <- row s+1 ; SB(0) ; compute(bankA) ;
//   load bankA <- row s+2 ; SB(0) ; compute(bankB)
// 2-step unroll => banks are distinct SSA values, zero rotation copies.
// Expected VGPR ~170-215 (grid caps occupancy at 1 wave/SIMD regardless).
// ---------------------------------------------------------------------------
__global__ __launch_bounds__(256, 1) void scan_kernel(
    const float* __restrict__ Wb, const int* __restrict__ qa_data,
    const u32* __restrict__ EAtab,
    const float* __restrict__ Mv0, float* __restrict__ MvSt,
    u16* __restrict__ RDIE, int CS, int s0, int first)
{
    __shared__ float wt[2][WT * WSTRIDE];   // 2 x 520 floats = 4160 B
    const int b = blockIdx.x;
    const int d = threadIdx.x;

    f2 mv[25];
    if (first) {
#pragma unroll
        for (int j = 0; j < 25; ++j) {
            mv[j].x = Mv0[(2 * j) * DV + d];
            mv[j].y = Mv0[(2 * j + 1) * DV + d];
        }
    } else {
#pragma unroll
        for (int j = 0; j < 25; ++j) {
            mv[j].x = MvSt[((size_t)b * MM + 2 * j) * DV + d];
            mv[j].y = MvSt[((size_t)b * MM + 2 * j + 1) * DV + d];
        }
    }

    const float* wbase = Wb + (size_t)b * CS * WSTRIDE;   // rows contiguous
    const int* qap = qa_data + (size_t)b * SQ + s0;
    u16* rp = RDIE + (size_t)b * CS * 384 + d;

    const int NT = CS / WT;
    const bool loader = (d < (WT * WSTRIDE / 4));   // 130 loader threads

    // Preload tile 0: W -> LDS buf0, ea -> regs (index then gather)
    if (loader) *(float4*)&wt[0][d * 4] = ld4(wbase + d * 4);
    u32 ea[WT];
    {
        int qi[WT];
#pragma unroll
        for (int i = 0; i < WT; ++i) qi[i] = qap[i];
#pragma unroll
        for (int i = 0; i < WT; ++i) ea[i] = EAtab[(size_t)qi[i] * DV + d];
    }
    __syncthreads();

    // one scan step computed from a pinned register bank
    auto STEP = [&](const float4* bk, u32 eav, int t) {
        float e = h2f((u16)(eav & 0xffff));
        float a = h2f((u16)(eav >> 16));
        f2 e2; e2.x = e; e2.y = e;
        f2 a2; a2.x = a; a2.y = a;
        f2 r0 = (f2)0.f, r1 = (f2)0.f, r2 = (f2)0.f, r3 = (f2)0.f;
#pragma unroll
        for (int j = 0; j < 25; ++j) {
            f2 w2;
            w2.x = CBF(bk, 2 * j);
            w2.y = CBF(bk, 2 * j + 1);
            if ((j & 3) == 0)      r0 += w2 * mv[j];
            else if ((j & 3) == 1) r1 += w2 * mv[j];
            else if ((j & 3) == 2) r2 += w2 * mv[j];
            else                   r3 += w2 * mv[j];
            f2 tt = a2 - e2 * mv[j];
            mv[j] += w2 * tt;
        }
        f2 rs = (r0 + r1) + (r2 + r3);
        rp[(size_t)t * 384] = f2h(rs.x + rs.y);
    };

    int cur = 0;
    for (int tile = 0; tile < NT; ++tile) {
        // Prefetch next tile (global -> regs); consumed after this tile
        float4 wreg;
        u32 ean[WT];
        const bool havenext = (tile + 1 < NT);
        if (havenext) {
            if (loader) wreg = ld4(wbase + (size_t)(tile + 1) * WT * WSTRIDE + d * 4);
            int qn[WT];
#pragma unroll
            for (int i = 0; i < WT; ++i) qn[i] = qap[(tile + 1) * WT + i];
#pragma unroll
            for (int i = 0; i < WT; ++i) ean[i] = EAtab[(size_t)qn[i] * DV + d];
        }

        // load step 0 into bank A; fence so the loads can't sink
        float4 cbA[13], cbB[13];
#pragma unroll
        for (int i = 0; i < 13; ++i) cbA[i] = *(const float4*)&wt[cur][i * 4];
        __builtin_amdgcn_sched_barrier(0);

#pragma unroll
        for (int s = 0; s < WT; s += 2) {
            // prefetch row s+1 into bank B, fence, compute step s from A
#pragma unroll
            for (int i = 0; i < 13; ++i)
                cbB[i] = *(const float4*)&wt[cur][(s + 1) * WSTRIDE + i * 4];
            __builtin_amdgcn_sched_barrier(0);
            STEP(cbA, ea[s], tile * WT + s);
            // prefetch row s+2 into bank A (clamped), fence, compute s+1 from B
            {
                const int r2 = (s + 2 < WT) ? (s + 2) : (WT - 1);
#pragma unroll
                for (int i = 0; i < 13; ++i)
                    cbA[i] = *(const float4*)&wt[cur][r2 * WSTRIDE + i * 4];
            }
            __builtin_amdgcn_sched_barrier(0);
            STEP(cbB, ea[s + 1], tile * WT + s + 1);
        }

        if (havenext) {
            if (loader) *(float4*)&wt[1 - cur][d * 4] = wreg;
#pragma unroll
            for (int i = 0; i < WT; ++i) ea[i] = ean[i];
            __syncthreads();
            cur ^= 1;
        }
    }

#pragma unroll
    for (int j = 0; j < 25; ++j) {
        MvSt[((size_t)b * MM + 2 * j) * DV + d]     = mv[j].x;
        MvSt[((size_t)b * MM + 2 * j + 1) * DV + d] = mv[j].y;
    }
}

// ---------------------------------------------------------------------------
// loss + outputs (pred partials read as float4 from bufP4; no atomics)
// ---------------------------------------------------------------------------
__global__ __launch_bounds__(256) void loss_part(
    const float* __restrict__ P4, const int* __restrict__ target,
    const float* __restrict__ pred_b, float* __restrict__ out,
    float* __restrict__ R2, int s0, int CS, int Nc)
{
    int l = blockIdx.x * 256 + threadIdx.x;
    float le = 0.f, mf = 0.f;
    if (l < Nc) {
        int n = gmap(l, s0, CS);
        float4 p4 = ld4(P4 + (size_t)l * 4);
        float p = (p4.x + p4.y) + (p4.z + p4.w) + pred_b[0];
        int t = target[n];
        float y = (t >= 1) ? (float)(t - 1) : 0.f;
        float sig = 1.f / (1.f + __expf(-p));
        if (t >= 1) {
            mf = 1.f;
            le = fmaxf(p, 0.f) + log1pf(__expf(-fabsf(p))) - p * y;
        }
        out[1 + n] = sig * mf;
        out[1 + NROWS + n] = y * mf;
    }
#pragma unroll
    for (int off = 32; off; off >>= 1) {
        le += __shfl_down(le, off);
        mf += __shfl_down(mf, off);
    }
    __shared__ float sl[4], sm[4];
    int wid = threadIdx.x >> 6;
    if ((threadIdx.x & 63) == 0) { sl[wid] = le; sm[wid] = mf; }
    __syncthreads();
    if (threadIdx.x == 0) {
        atomicAdd(R2, sl[0] + sl[1] + sl[2] + sl[3]);
        atomicAdd(R2 + 1, sm[0] + sm[1] + sm[2] + sm[3]);
    }
}

__global__ void loss_fin(const float* __restrict__ R2, float* __restrict__ out)
{
    out[0] = R2[0] / fmaxf(R2[1], 1.f);
}

// ---------------------------------------------------------------------------
extern "C" void kernel_launch(void* const* d_in, const int* in_sizes, int n_in,
                              void* d_out, int out_size, void* d_ws, size_t ws_size,
                              hipStream_t stream)
{
    const int* q_data       = (const int*)d_in[0];
    const int* qa_data      = (const int*)d_in[1];
    const int* target       = (const int*)d_in[2];
    const int* time_data    = (const int*)d_in[3];
    const int* attempt_data = (const int*)d_in[4];
    const int* hint_data    = (const int*)d_in[5];
    const int* hintT_data   = (const int*)d_in[6];
    const float* q_emb    = (const float*)d_in[7];
    const float* qa_emb   = (const float*)d_in[8];
    const float* time_emb = (const float*)d_in[9];
    const float* att_emb  = (const float*)d_in[10];
    const float* ht_emb   = (const float*)d_in[11];
    const float* Mk       = (const float*)d_in[12];
    const float* Mv0      = (const float*)d_in[13];
    const float* diff_W   = (const float*)d_in[14];
    const float* diff_b   = (const float*)d_in[15];
    const float* diff2_W  = (const float*)d_in[16];
    const float* diff2_b  = (const float*)d_in[17];
    const float* erase_W  = (const float*)d_in[18];
    const float* erase_b  = (const float*)d_in[19];
    const float* add_W    = (const float*)d_in[20];
    const float* add_b    = (const float*)d_in[21];
    const float* read_W   = (const float*)d_in[22];
    const float* read_b   = (const float*)d_in[23];
    const float* pred_W   = (const float*)d_in[24];
    const float* pred_b   = (const float*)d_in[25];
    float* out = (float*)d_out;
    (void)in_sizes; (void)n_in; (void)out_size;

    // Adaptive chunking over S (CS must be divisible by WT=10).
    // Per-row bytes: wbuf 208 + bufP4 16 + Xp 512 + RDIE 768 = 1504
    static const int cs_opts[] = {500, 250, 100, 50, 20, 10};
    const size_t FIXED = 44800000ull;
    int CS = 0;
    for (int i = 0; i < 6; ++i) {
        size_t need = (size_t)NB * cs_opts[i] * 1504ull + FIXED;
        if (need <= ws_size) { CS = cs_opts[i]; break; }
    }
    if (CS == 0) return;
    const int NCH = SQ / CS;
    const int Nc = NB * CS;

    // Workspace layout (16B-aligned sections)
    float* MvSt  = (float*)d_ws;                         // [NB*MM*DV]
    float* wbuf  = MvSt + (size_t)NB * MM * DV;          // [Nc*52]
    float* bufP4 = wbuf + (size_t)Nc * WSTRIDE;          // [Nc*4]
    float* bufR2 = bufP4 + (size_t)Nc * 4;               // [4]
    u16*  Xp     = (u16*)(bufR2 + 4);                    // [2Nc*128]
    u16*  RDIE   = Xp + (size_t)2 * Nc * 128;            // [Nc*384]
    u16*  dWh    = RDIE + (size_t)Nc * 384;              // 16384
    u16*  d2Wh   = dWh + 16384;                          // 16384
    u16*  eWh    = d2Wh + 16384;                         // 65536
    u16*  aWh    = eWh + 65536;                          // 65536
    u16*  rWh    = aWh + 65536;                          // 196608
    u16*  qaEh   = rWh + 196608;                         // 5,120,256
    u16*  Mkh    = qaEh + 5120256;                       // 8,192 (64x128)
    u32*  EAtab  = (u32*)(Mkh + 8192);                   // [NQA*256] u32 = 20.6 MB

    // Fused one-time weight conversions (5 matrices -> contiguous dWh..rWh)
    wcvt<<<352, 256, 0, stream>>>(diff_W, diff2_W, erase_W, add_W, read_W, dWh);
    cvt16<<<5001, 256, 0, stream>>>(qa_emb, qaEh, 5120256 / 4);
    mkcvt<<<8, 256, 0, stream>>>(Mk, Mkh);
    hipMemsetAsync(bufR2, 0, 4 * sizeof(float), stream);

    // One-time e/a gate TABLE over all distinct qa indices (NQA rows)
    gemm16<4><<<dim3(4, NQA / 128), 256, 0, stream>>>(
        qaEh, eWh, aWh, erase_b, add_b, nullptr, nullptr,
        (u16*)EAtab, nullptr, 256);

    for (int c = 0; c < NCH; ++c) {
        const int s0 = c * CS;

        prep128<<<Nc / 8, 256, 0, stream>>>(
            q_data, time_data, attempt_data, hint_data, hintT_data,
            q_emb, time_emb, att_emb, ht_emb, Xp, RDIE, s0, CS, Nc);

        // FUSED G1+G2: tf (rows<Nc) and x3 (rows>=Nc) in one pass
        gemm12<<<2 * Nc / 128, 256, 0, stream>>>(
            Xp, dWh, d2Wh, diff_b, diff2_b, Xp, RDIE, Nc);

        // FUSED G3+wsoftmax: qp in LDS; ie -> RDIE[:,256:384); w -> wbuf
        gemm3w<<<Nc / 128, 256, 0, stream>>>(
            Xp + (size_t)Nc * 128, dWh, diff_b, Mkh,
            time_data, time_emb, Xp, RDIE, wbuf, s0, CS);

        // scan -> RD fp16 into RDIE[:,0:256); e/a gathered from EAtab
        scan_kernel<<<NB, DV, 0, stream>>>(
            wbuf, qa_data, EAtab, Mv0, MvSt, RDIE, CS, s0, c == 0 ? 1 : 0);

        // G5: rc = tanh([rd|ie] @ read_W^T + b); pred partials -> bufP4
        gemm16<5><<<dim3(4, Nc / 128), 256, 0, stream>>>(
            RDIE, rWh, nullptr, read_b, nullptr, nullptr, bufP4,
            nullptr, pred_W, 384);

        loss_part<<<Nc / 256, 256, 0, stream>>>(bufP4, target, pred_b, out, bufR2, s0, CS, Nc);
    }

    loss_fin<<<1, 1, 0, stream>>>(bufR2, out);
}